// Round 1
// baseline (3728.001 us; speedup 1.0000x reference)
//
#include <hip/hip_runtime.h>
#include <hip/hip_bf16.h>
#include <cstdint>
#include <cstddef>

#define N_MOLS 256
#define N_PER  32
#define NN     8192
#define EDGES  253952
#define EPM    992       // edges per molecule = 32*31
#define SDIM_  256
#define EDIM_  32
#define NAF_   16
#define LAYERS_ 5
#define TEDGE  16        // edges per tile in edge kernels
#define NTILE  62        // 992/16

__device__ __forceinline__ float silu_f(float x) {
    return x / (1.f + __expf(-x));
}
__device__ __forceinline__ unsigned short f2bf(float x) {
    union { float f; uint32_t u; } v; v.f = x;
    uint32_t u = v.u;
    uint32_t r = (u + 0x7FFFu + ((u >> 16) & 1u)) >> 16;
    return (unsigned short)r;
}
__device__ __forceinline__ float bf2f(unsigned short h) {
    union { uint32_t u; float f; } v; v.u = ((uint32_t)h) << 16; return v.f;
}
__device__ __forceinline__ void unpack2(uint32_t u, float& lo, float& hi) {
    union { uint32_t u; float f; } a, b;
    a.u = u << 16; b.u = u & 0xFFFF0000u;
    lo = a.f; hi = b.f;
}

// ---------------------------------------------------------------------------
// Kernel A: node init.  h = [x|z] @ Wam + bam ; s = h[:,:256]; pos = rot[mol] @ h[:,256:259]
// one block per node, 256 threads.
// ---------------------------------------------------------------------------
__global__ __launch_bounds__(256) void node_init(
    const float* __restrict__ x, const float* __restrict__ z,
    const float* __restrict__ rot, const float* __restrict__ Wam,
    const float* __restrict__ bam, float* __restrict__ s, float* __restrict__ pos)
{
    const int n = blockIdx.x, t = threadIdx.x;
    __shared__ float xz[80];
    __shared__ float praw[3];
    if (t < 16)      xz[t] = x[n * 16 + t];
    else if (t < 80) xz[t] = z[n * 64 + (t - 16)];
    __syncthreads();
    float acc = bam[t];
    #pragma unroll 8
    for (int k = 0; k < 80; ++k) acc += xz[k] * Wam[k * 259 + t];
    s[(size_t)n * SDIM_ + t] = acc;
    if (t < 3) {
        const int j2 = 256 + t;
        float a2 = bam[j2];
        for (int k = 0; k < 80; ++k) a2 += xz[k] * Wam[k * 259 + j2];
        praw[t] = a2;
    }
    __syncthreads();
    if (t < 3) {
        const int mol = n >> 5;
        float p = 0.f;
        for (int jj = 0; jj < 3; ++jj) p += rot[mol * 9 + t * 3 + jj] * praw[jj];
        pos[n * 3 + t] = p;
    }
}

// ---------------------------------------------------------------------------
// Kernel B: edge feature init. e = edge_attr @ Wbm + bbm   [E,5]@[5,32]
// thread per (edge, c) pair.
// ---------------------------------------------------------------------------
__global__ __launch_bounds__(256) void edge_init(
    const float* __restrict__ ea, const float* __restrict__ Wbm,
    const float* __restrict__ bbm, float* __restrict__ ebuf)
{
    const int gid = blockIdx.x * 256 + threadIdx.x;
    const int edge = gid >> 5, c = gid & 31;
    float acc = bbm[c];
    #pragma unroll
    for (int k = 0; k < 5; ++k) acc += ea[(size_t)edge * 5 + k] * Wbm[k * 32 + c];
    ebuf[(size_t)gid] = acc;
}

// ---------------------------------------------------------------------------
// Generic fp32 tiled GEMM: C[M,N] = act( alpha * A@B + bias )  (+= if ACCUM)
// A row-major [M,K] (lda=K), B row-major with row stride ldb (use cols 0..N-1
// starting at B), C row-major ldc=N.  64x64 tile, 256 threads, 4x4 microtile.
// Requires M%64==0, N%64==0, K%16==0.
// ---------------------------------------------------------------------------
template<int ACT, int ACCUM>
__global__ __launch_bounds__(256) void gemm64(
    const float* __restrict__ A, const float* __restrict__ B,
    float* __restrict__ C, const float* __restrict__ bias,
    int K, int N, int ldb, float alpha)
{
    const int n0 = blockIdx.x * 64, m0 = blockIdx.y * 64;
    const int t = threadIdx.x, tx = t & 15, ty = t >> 4;
    __shared__ float As[16][68];
    __shared__ float Bs[16][68];
    float acc[4][4] = {};
    for (int k0 = 0; k0 < K; k0 += 16) {
        {   // A tile 64x16 (store transposed As[k][m])
            const int r = t >> 2, q = t & 3;
            const float4 av = *(const float4*)(A + (size_t)(m0 + r) * K + k0 + q * 4);
            As[q * 4 + 0][r] = av.x; As[q * 4 + 1][r] = av.y;
            As[q * 4 + 2][r] = av.z; As[q * 4 + 3][r] = av.w;
        }
        {   // B tile 16x64
            const int nc = t & 63;
            #pragma unroll
            for (int it = 0; it < 4; ++it) {
                const int kr = (t >> 6) + it * 4;
                Bs[kr][nc] = B[(size_t)(k0 + kr) * ldb + n0 + nc];
            }
        }
        __syncthreads();
        #pragma unroll
        for (int kk = 0; kk < 16; ++kk) {
            const float4 a4 = *(const float4*)&As[kk][ty * 4];
            const float4 b4 = *(const float4*)&Bs[kk][tx * 4];
            const float aa[4] = {a4.x, a4.y, a4.z, a4.w};
            const float bb[4] = {b4.x, b4.y, b4.z, b4.w};
            #pragma unroll
            for (int i2 = 0; i2 < 4; ++i2)
                #pragma unroll
                for (int j2 = 0; j2 < 4; ++j2)
                    acc[i2][j2] += aa[i2] * bb[j2];
        }
        __syncthreads();
    }
    #pragma unroll
    for (int i2 = 0; i2 < 4; ++i2) {
        const int m = m0 + ty * 4 + i2;
        #pragma unroll
        for (int j2 = 0; j2 < 4; ++j2) {
            const int n = n0 + tx * 4 + j2;
            float v = alpha * acc[i2][j2];
            if (bias) v += bias[n];
            if (ACT) v = silu_f(v);
            if (ACCUM) C[(size_t)m * N + n] += v;
            else       C[(size_t)m * N + n] = v;
        }
    }
}

// ---------------------------------------------------------------------------
// Per-layer fused edge kernel. One block per molecule, 512 threads.
//  For each edge (src,tgt):  pre_j = SA[src][j]+SB[tgt][j]+sum_k e[k]*W1c[k][j]
//                                    + d*w1d[j] + a*w1a[j] + b1[j]
//  hdn = silu(pre)                          (stored bf16 in LDS)
//  e_new = e + hdn@W2[:,321:353] + b2e      (written to global)
//  p     = hdn@W2[:,320] + b2p
//  H[tgt]    += hdn        (LDS accumulator -> Hbuf)
//  pacc[tgt] += r_norm * p (LDS accumulator -> pdelta)
// ---------------------------------------------------------------------------
__global__ __launch_bounds__(512) void edge_kernel(
    const float* __restrict__ SA, const float* __restrict__ SB,
    const float* __restrict__ pos, float* __restrict__ ebuf,
    const float* __restrict__ W1, const float* __restrict__ b1,
    const float* __restrict__ W2, const float* __restrict__ b2,
    float* __restrict__ Hbuf, float* __restrict__ pdelta)
{
    const int mol = blockIdx.x;
    const int t = threadIdx.x;
    const int node0 = mol * N_PER;

    __shared__ float sH[N_PER][SDIM_];           // 32 KB accumulator
    __shared__ unsigned short sW2T[33][264];     // bf16 W2 cols 320..352, [c][k]
    __shared__ unsigned short sHdn[TEDGE][264];  // bf16 hdn tile
    __shared__ float sE[TEDGE][EDIM_];
    __shared__ float sPos[N_PER][3];
    __shared__ float sPacc[N_PER][3];
    __shared__ float sD[TEDGE], sAv[TEDGE], sP[TEDGE];
    __shared__ float sRN[TEDGE][3];
    __shared__ float sB2e[33];

    for (int i = t; i < N_PER * SDIM_; i += 512) ((float*)sH)[i] = 0.f;
    for (int i = t; i < 33 * SDIM_; i += 512) {
        const int c = i >> 8, jj = i & 255;
        sW2T[c][jj] = f2bf(W2[(size_t)jj * 353 + 320 + c]);
    }
    if (t < 33) sB2e[t] = b2[320 + t];
    if (t < N_PER * 3) { ((float*)sPos)[t] = pos[node0 * 3 + t]; ((float*)sPacc)[t] = 0.f; }

    const int j = t & 255;
    float w1c[EDIM_];
    #pragma unroll
    for (int k = 0; k < EDIM_; ++k) w1c[k] = W1[(size_t)(512 + k) * SDIM_ + j];
    const float w1d = W1[(size_t)544 * SDIM_ + j];
    const float w1a = W1[(size_t)545 * SDIM_ + j];
    const float b1j = b1[j];
    __syncthreads();

    for (int ti = 0; ti < NTILE; ++ti) {
        const int e0 = ti * TEDGE;
        // stage e tile (512 floats == blockDim)
        ((float*)sE)[t] = ebuf[(size_t)(mol * EPM + e0) * EDIM_ + t];
        if (t < TEDGE) {   // geometry
            const int eid = e0 + t;
            const int s_ = eid / 31, r_ = eid - 31 * s_;
            const int tg = r_ + (r_ >= s_ ? 1 : 0);
            const float ax = sPos[tg][0], ay = sPos[tg][1], az = sPos[tg][2];
            const float bx = sPos[s_][0], by = sPos[s_][1], bz = sPos[s_][2];
            const float rx = ax - bx, ry = ay - by, rz = az - bz;
            const float av = ax * bx + ay * by + az * bz;
            const float rr = rx * rx + ry * ry + rz * rz;
            const float dd = sqrtf(fmaxf(rr, 1e-6f));
            const float inv = 1.f / (1.f + dd);
            sD[t] = dd; sAv[t] = av;
            sRN[t][0] = rx * inv; sRN[t][1] = ry * inv; sRN[t][2] = rz * inv;
        }
        __syncthreads();
        // phase 1: hdn = silu(pre), 2 edge-groups x 256 channels
        for (int el = (t >> 8); el < TEDGE; el += 2) {
            const int eid = e0 + el;
            const int s_ = eid / 31, r_ = eid - 31 * s_;
            const int tg = r_ + (r_ >= s_ ? 1 : 0);
            float acc = b1j + SA[(size_t)(node0 + s_) * SDIM_ + j]
                            + SB[(size_t)(node0 + tg) * SDIM_ + j]
                            + sD[el] * w1d + sAv[el] * w1a;
            #pragma unroll
            for (int k = 0; k < EDIM_; ++k) acc += sE[el][k] * w1c[k];
            sHdn[el][j] = f2bf(silu_f(acc));
        }
        __syncthreads();
        // phase 2: m_e (32 cols) and p (col 0 == W2 col 320), K=256
        if (t < 264) {
            const int el = t / 33, c = t - 33 * (t / 33);
            float acc0 = 0.f, acc1 = 0.f;
            #pragma unroll 4
            for (int k = 0; k < SDIM_; k += 8) {
                const uint4 w  = *(const uint4*)&sW2T[c][k];
                const uint4 h0 = *(const uint4*)&sHdn[el][k];
                const uint4 h1 = *(const uint4*)&sHdn[el + 8][k];
                const uint32_t wu[4]  = {w.x, w.y, w.z, w.w};
                const uint32_t h0u[4] = {h0.x, h0.y, h0.z, h0.w};
                const uint32_t h1u[4] = {h1.x, h1.y, h1.z, h1.w};
                #pragma unroll
                for (int q = 0; q < 4; ++q) {
                    float wl, wh, g0l, g0h, g1l, g1h;
                    unpack2(wu[q], wl, wh);
                    unpack2(h0u[q], g0l, g0h);
                    unpack2(h1u[q], g1l, g1h);
                    acc0 += g0l * wl + g0h * wh;
                    acc1 += g1l * wl + g1h * wh;
                }
            }
            const float r0 = acc0 + sB2e[c], r1 = acc1 + sB2e[c];
            if (c == 0) { sP[el] = r0; sP[el + 8] = r1; }
            else {
                const int ci = c - 1;
                const int geid0 = mol * EPM + e0 + el;
                ebuf[(size_t)geid0 * EDIM_ + ci]       = sE[el][ci] + r0;
                ebuf[(size_t)(geid0 + 8) * EDIM_ + ci] = sE[el + 8][ci] + r1;
            }
        }
        __syncthreads();
        // accumulate H and pos-delta (per-column ownership -> no races)
        for (int el = 0; el < TEDGE; ++el) {
            const int eid = e0 + el;
            const int s_ = eid / 31, r_ = eid - 31 * s_;
            const int tg = r_ + (r_ >= s_ ? 1 : 0);
            if (t < SDIM_) sH[tg][t] += bf2f(sHdn[el][t]);
            else if (t < SDIM_ + 3) {
                const int dd = t - SDIM_;
                sPacc[tg][dd] += sRN[el][dd] * sP[el];
            }
        }
        __syncthreads();
    }
    for (int i = t; i < N_PER * SDIM_; i += 512)
        Hbuf[(size_t)node0 * SDIM_ + i] = ((float*)sH)[i];
    if (t < N_PER * 3) pdelta[node0 * 3 + t] = ((float*)sPacc)[t];
}

// ---------------------------------------------------------------------------
// pos += pdelta / 31
// ---------------------------------------------------------------------------
__global__ __launch_bounds__(256) void pos_update(float* __restrict__ pos,
                                                  const float* __restrict__ pd)
{
    const int i = blockIdx.x * 256 + threadIdx.x;
    pos[i] += pd[i] * (1.f / 31.f);
}

__global__ __launch_bounds__(256) void pos_copy(const float* __restrict__ pos,
                                                float* __restrict__ out)
{
    const int i = blockIdx.x * 256 + threadIdx.x;
    out[i] = pos[i];
}

// ---------------------------------------------------------------------------
// atoms = tmp @ Wh2 + bh2, tmp = silu(s@Wh1+bh1) already computed. N=16.
// ---------------------------------------------------------------------------
__global__ __launch_bounds__(256) void atoms_kernel(
    const float* __restrict__ tmp, const float* __restrict__ Wh2,
    const float* __restrict__ bh2, float* __restrict__ outA)
{
    const int gid = blockIdx.x * 256 + threadIdx.x;
    const int n = gid >> 4, o = gid & 15;
    float acc = bh2[o];
    #pragma unroll 8
    for (int k = 0; k < SDIM_; ++k) acc += tmp[(size_t)n * SDIM_ + k] * Wh2[k * NAF_ + o];
    outA[gid] = acc;
}

// ---------------------------------------------------------------------------
// Final bond head. One block per molecule, 256 threads.
//  pre_j = U[src][j]+U[tgt][j] + sum_k e[k]*We1[256+k][j] + d*We1[288][j] + be1[j]
//  bonds = silu(pre) @ We2 + be2
// ---------------------------------------------------------------------------
__global__ __launch_bounds__(256) void bond_kernel(
    const float* __restrict__ U, const float* __restrict__ pos,
    const float* __restrict__ ebuf, const float* __restrict__ We1,
    const float* __restrict__ be1, const float* __restrict__ We2,
    const float* __restrict__ be2, float* __restrict__ outB)
{
    const int mol = blockIdx.x, t = threadIdx.x;
    const int node0 = mol * N_PER;
    __shared__ float sU[N_PER][128];
    __shared__ float sHb[TEDGE][132];
    __shared__ float sE[TEDGE][EDIM_];
    __shared__ float sW25T[5][132];
    __shared__ float sPos[N_PER][3];
    __shared__ float sD[TEDGE];

    for (int i = t; i < N_PER * 128; i += 256) ((float*)sU)[i] = U[(size_t)node0 * 128 + i];
    for (int i = t; i < 5 * 128; i += 256) {
        const int o = i >> 7, jj = i & 127;
        sW25T[o][jj] = We2[jj * 5 + o];
    }
    if (t < N_PER * 3) ((float*)sPos)[t] = pos[node0 * 3 + t];

    const int j = t & 127;
    float we1e[EDIM_];
    #pragma unroll
    for (int k = 0; k < EDIM_; ++k) we1e[k] = We1[(size_t)(SDIM_ + k) * 128 + j];
    const float we1d = We1[(size_t)288 * 128 + j];
    const float be1j = be1[j];
    __syncthreads();

    for (int ti = 0; ti < NTILE; ++ti) {
        const int e0 = ti * TEDGE;
        for (int i = t; i < TEDGE * EDIM_; i += 256)
            ((float*)sE)[i] = ebuf[(size_t)(mol * EPM + e0) * EDIM_ + i];
        if (t < TEDGE) {
            const int eid = e0 + t;
            const int s_ = eid / 31, r_ = eid - 31 * s_;
            const int tg = r_ + (r_ >= s_ ? 1 : 0);
            const float rx = sPos[tg][0] - sPos[s_][0];
            const float ry = sPos[tg][1] - sPos[s_][1];
            const float rz = sPos[tg][2] - sPos[s_][2];
            const float rr = rx * rx + ry * ry + rz * rz;
            sD[t] = sqrtf(fmaxf(rr, 1e-6f));
        }
        __syncthreads();
        for (int el = (t >> 7); el < TEDGE; el += 2) {
            const int eid = e0 + el;
            const int s_ = eid / 31, r_ = eid - 31 * s_;
            const int tg = r_ + (r_ >= s_ ? 1 : 0);
            float acc = be1j + sU[s_][j] + sU[tg][j] + sD[el] * we1d;
            #pragma unroll
            for (int k = 0; k < EDIM_; ++k) acc += sE[el][k] * we1e[k];
            sHb[el][j] = silu_f(acc);
        }
        __syncthreads();
        if (t < TEDGE * 5) {
            const int el = t / 5, o = t - 5 * (t / 5);
            float acc = 0.f;
            #pragma unroll 8
            for (int k = 0; k < 128; k += 4) {
                const float4 h = *(const float4*)&sHb[el][k];
                const float4 w = *(const float4*)&sW25T[o][k];
                acc += h.x * w.x + h.y * w.y + h.z * w.z + h.w * w.w;
            }
            outB[(size_t)(mol * EPM + e0 + el) * 5 + o] = acc + be2[o];
        }
        __syncthreads();
    }
}

// ---------------------------------------------------------------------------
extern "C" void kernel_launch(void* const* d_in, const int* in_sizes, int n_in,
                              void* d_out, int out_size, void* d_ws, size_t ws_size,
                              hipStream_t stream) {
    const float* x   = (const float*)d_in[0];
    const float* z   = (const float*)d_in[1];
    const float* rot = (const float*)d_in[2];
    const float* ea  = (const float*)d_in[4];
    const float* Wam = (const float*)d_in[6];
    const float* bam = (const float*)d_in[7];
    const float* Wbm = (const float*)d_in[8];
    const float* bbm = (const float*)d_in[9];
    const float* gW1 = (const float*)d_in[10];
    const float* gb1 = (const float*)d_in[11];
    const float* gW2 = (const float*)d_in[12];
    const float* gb2 = (const float*)d_in[13];
    const float* Wh1 = (const float*)d_in[14];
    const float* bh1 = (const float*)d_in[15];
    const float* Wh2 = (const float*)d_in[16];
    const float* bh2 = (const float*)d_in[17];
    const float* We1 = (const float*)d_in[18];
    const float* be1 = (const float*)d_in[19];
    const float* We2 = (const float*)d_in[20];
    const float* be2 = (const float*)d_in[21];
    float* out = (float*)d_out;

    float* ws  = (float*)d_ws;
    float* s   = ws;                    // 8192*256
    float* pos = ws + 2097152;          // 8192*3
    float* e   = ws + 2121728;          // E*32
    float* SA  = ws + 10248192;         // 8192*256
    float* SB  = ws + 12345344;         // 8192*256
    float* H   = ws + 14442496;         // 8192*256
    float* pd  = ws + 16539648;         // 8192*3
    float* tmp = SA;                    // reuse after layers
    float* U   = H;                     // reuse after layers

    node_init<<<NN, 256, 0, stream>>>(x, z, rot, Wam, bam, s, pos);
    edge_init<<<(EDGES * EDIM_) / 256, 256, 0, stream>>>(ea, Wbm, bbm, e);

    for (int l = 0; l < LAYERS_; ++l) {
        const float* W1 = gW1 + (size_t)l * 546 * 256;
        const float* b1 = gb1 + l * 256;
        const float* W2 = gW2 + (size_t)l * 256 * 353;
        const float* b2 = gb2 + l * 353;
        // SA = s @ W1[0:256], SB = s @ W1[256:512]
        gemm64<0,0><<<dim3(4, 128), 256, 0, stream>>>(s, W1,             SA, nullptr, 256, 256, 256, 1.f);
        gemm64<0,0><<<dim3(4, 128), 256, 0, stream>>>(s, W1 + 256 * 256, SB, nullptr, 256, 256, 256, 1.f);
        edge_kernel<<<N_MOLS, 512, 0, stream>>>(SA, SB, pos, e, W1, b1, W2, b2, H, pd);
        // s += (H @ W2[:,0:256]) / 31 + b2[0:256]
        gemm64<0,1><<<dim3(4, 128), 256, 0, stream>>>(H, W2, s, b2, 256, 256, 353, 1.f / 31.f);
        pos_update<<<96, 256, 0, stream>>>(pos, pd);
    }

    // atoms = silu(s@Wh1+bh1)@Wh2 + bh2
    gemm64<1,0><<<dim3(4, 128), 256, 0, stream>>>(s, Wh1, tmp, bh1, 256, 256, 256, 1.f);
    atoms_kernel<<<512, 256, 0, stream>>>(tmp, Wh2, bh2, out);

    // bonds: U = s @ We1[0:256]  then fused edge head
    gemm64<0,0><<<dim3(2, 128), 256, 0, stream>>>(s, We1, U, nullptr, 256, 128, 128, 1.f);
    bond_kernel<<<N_MOLS, 256, 0, stream>>>(U, pos, e, We1, be1, We2, be2, out + 131072);

    pos_copy<<<96, 256, 0, stream>>>(pos, out + 131072 + 1269760);
}

// Round 2
// 1410.835 us; speedup vs baseline: 2.6424x; 2.6424x over previous
//
#include <hip/hip_runtime.h>
#include <hip/hip_bf16.h>
#include <cstdint>
#include <cstddef>

#define N_MOLS 256
#define N_PER  32
#define NN     8192
#define EDGES  253952
#define SDIM_  256
#define EDIM_  32
#define NAF_   16
#define LAYERS_ 5

typedef __attribute__((ext_vector_type(8)))  short bf16x8;
typedef __attribute__((ext_vector_type(16))) float f32x16;

__device__ __forceinline__ float silu_f(float x) {
    return x / (1.f + __expf(-x));
}
__device__ __forceinline__ short bfc(float f) {
    __hip_bfloat16 h = __float2bfloat16(f);
    return __builtin_bit_cast(short, h);
}
#define ONEBF ((short)0x3F80)

// ---------------------------------------------------------------------------
// node init: h = [x|z]@Wam+bam; s = h[:,:256]; pos = rot[mol]@h[:,256:259]
// ---------------------------------------------------------------------------
__global__ __launch_bounds__(256) void node_init(
    const float* __restrict__ x, const float* __restrict__ z,
    const float* __restrict__ rot, const float* __restrict__ Wam,
    const float* __restrict__ bam, float* __restrict__ s, float* __restrict__ pos)
{
    const int n = blockIdx.x, t = threadIdx.x;
    __shared__ float xz[80];
    __shared__ float praw[3];
    if (t < 16)      xz[t] = x[n * 16 + t];
    else if (t < 80) xz[t] = z[n * 64 + (t - 16)];
    __syncthreads();
    float acc = bam[t];
    #pragma unroll 8
    for (int k = 0; k < 80; ++k) acc += xz[k] * Wam[k * 259 + t];
    s[(size_t)n * SDIM_ + t] = acc;
    if (t < 3) {
        const int j2 = 256 + t;
        float a2 = bam[j2];
        for (int k = 0; k < 80; ++k) a2 += xz[k] * Wam[k * 259 + j2];
        praw[t] = a2;
    }
    __syncthreads();
    if (t < 3) {
        const int mol = n >> 5;
        float p = 0.f;
        for (int jj = 0; jj < 3; ++jj) p += rot[mol * 9 + t * 3 + jj] * praw[jj];
        pos[n * 3 + t] = p;
    }
}

// ---------------------------------------------------------------------------
// edge feature init into tgt-major layout: e[((mol*32+n)*31+rr)*32+c]
// block per tile (mol,n): 8192 blocks.
// ---------------------------------------------------------------------------
__global__ __launch_bounds__(256) void edge_init2(
    const float* __restrict__ ea, const float* __restrict__ Wbm,
    const float* __restrict__ bbm, float* __restrict__ ebuf)
{
    const int tile = blockIdx.x;          // mol*32 + n
    const int mol = tile >> 5, n = tile & 31;
    const int t = threadIdx.x;
    for (int i = t; i < 31 * 32; i += 256) {
        const int rr = i >> 5, c = i & 31;
        const int s_ = rr + (rr >= n ? 1 : 0);
        const int ge = (mol * 32 + s_) * 31 + (n - (n > s_ ? 1 : 0));
        float acc = bbm[c];
        #pragma unroll
        for (int k = 0; k < 5; ++k) acc += ea[(size_t)ge * 5 + k] * Wbm[k * 32 + c];
        ebuf[(size_t)tile * 31 * 32 + i] = acc;
    }
}

// ---------------------------------------------------------------------------
// fp32 tiled GEMM (unchanged from R1): C = act(alpha*A@B + bias) (+= if ACCUM)
// ---------------------------------------------------------------------------
template<int ACT, int ACCUM>
__global__ __launch_bounds__(256) void gemm64(
    const float* __restrict__ A, const float* __restrict__ B,
    float* __restrict__ C, const float* __restrict__ bias,
    int K, int N, int ldb, float alpha)
{
    const int n0 = blockIdx.x * 64, m0 = blockIdx.y * 64;
    const int t = threadIdx.x, tx = t & 15, ty = t >> 4;
    __shared__ float As[16][68];
    __shared__ float Bs[16][68];
    float acc[4][4] = {};
    for (int k0 = 0; k0 < K; k0 += 16) {
        {
            const int r = t >> 2, q = t & 3;
            const float4 av = *(const float4*)(A + (size_t)(m0 + r) * K + k0 + q * 4);
            As[q * 4 + 0][r] = av.x; As[q * 4 + 1][r] = av.y;
            As[q * 4 + 2][r] = av.z; As[q * 4 + 3][r] = av.w;
        }
        {
            const int nc = t & 63;
            #pragma unroll
            for (int it = 0; it < 4; ++it) {
                const int kr = (t >> 6) + it * 4;
                Bs[kr][nc] = B[(size_t)(k0 + kr) * ldb + n0 + nc];
            }
        }
        __syncthreads();
        #pragma unroll
        for (int kk = 0; kk < 16; ++kk) {
            const float4 a4 = *(const float4*)&As[kk][ty * 4];
            const float4 b4 = *(const float4*)&Bs[kk][tx * 4];
            const float aa[4] = {a4.x, a4.y, a4.z, a4.w};
            const float bb[4] = {b4.x, b4.y, b4.z, b4.w};
            #pragma unroll
            for (int i2 = 0; i2 < 4; ++i2)
                #pragma unroll
                for (int j2 = 0; j2 < 4; ++j2)
                    acc[i2][j2] += aa[i2] * bb[j2];
        }
        __syncthreads();
    }
    #pragma unroll
    for (int i2 = 0; i2 < 4; ++i2) {
        const int m = m0 + ty * 4 + i2;
        #pragma unroll
        for (int j2 = 0; j2 < 4; ++j2) {
            const int n = n0 + tx * 4 + j2;
            float v = alpha * acc[i2][j2];
            if (bias) v += bias[n];
            if (ACT) v = silu_f(v);
            if (ACCUM) C[(size_t)m * N + n] += v;
            else       C[(size_t)m * N + n] = v;
        }
    }
}

// ---------------------------------------------------------------------------
// MFMA edge kernel. Block = 1 molecule, 4 waves; wave processes tgt-tiles
// n = wave, wave+4, ... Each tile: 31 in-edges (+1 pad row).
//   phase A: pre[32e][256] = Ageo[32][80] @ Bg[80][256] + (SB[n]+b1)
//            Ageo rows: [e(32) | d a 0*14 | onehot_src(32)]
//            Bg = [W1c(32); w1d; w1a; 0*14; SA_mol(32)]  (LDS, swizzled)
//   hdn = silu(pre)  -> H (reg reduce), p-partial, bf16 -> per-wave LDS chunk
//   phase C: m_e[32e][32] = hdn @ W2e  (W2e frags preloaded in VGPRs)
//   e += m_e + b2e; pdelta[n] = sum rn*p; H -> Hbuf
// ---------------------------------------------------------------------------
__global__ __launch_bounds__(256) void edge_mfma(
    const float* __restrict__ SA, const float* __restrict__ SB,
    const float* __restrict__ pos, float* __restrict__ ebuf,
    const float* __restrict__ W1, const float* __restrict__ b1,
    const float* __restrict__ W2, const float* __restrict__ b2,
    float* __restrict__ Hbuf, float* __restrict__ pdelta)
{
    const int mol = blockIdx.x;
    const int t = threadIdx.x;
    const int wave = t >> 6, lane = t & 63;
    const int l = lane & 31, half = lane >> 5;
    const int node0 = mol * 32;

    __shared__ __align__(16) short sBg[256][88];      // 11 slots x 8 shorts, swizzled
    __shared__ __align__(16) short sHdn[4][32][40];   // per-wave transpose chunk
    __shared__ float sPosS[32][4];
    __shared__ float sRn[4][32][4];

    // ---- stage Bg: thread t owns row j = t ----
    {
        const int j = t;
        for (int k = 0; k < 80; ++k) {
            float v;
            if (k < 32)       v = W1[(size_t)(512 + k) * 256 + j];
            else if (k == 32) v = W1[(size_t)544 * 256 + j];
            else if (k == 33) v = W1[(size_t)545 * 256 + j];
            else if (k < 48)  v = 0.f;
            else              v = SA[(size_t)(node0 + (k - 48)) * 256 + j];
            const int slot = ((k >> 3) + 3 * ((j >> 3) & 3)) % 11;
            sBg[j][slot * 8 + (k & 7)] = bfc(v);
        }
    }
    if (t < 96) sPosS[t / 3][t % 3] = pos[node0 * 3 + t];

    // ---- preload W2e B-fragments (c = l), w2p, b1, b2 ----
    bf16x8 w2efr[16];
    #pragma unroll
    for (int kk = 0; kk < 16; ++kk) {
        #pragma unroll
        for (int jj = 0; jj < 8; ++jj) {
            const int j = kk * 16 + half * 8 + jj;
            w2efr[kk][jj] = bfc(W2[(size_t)j * 353 + 321 + l]);
        }
    }
    float w2pv[8], b1v[8];
    #pragma unroll
    for (int cb = 0; cb < 8; ++cb) {
        w2pv[cb] = W2[(size_t)(cb * 32 + l) * 353 + 320];
        b1v[cb]  = b1[cb * 32 + l];
    }
    const float b2e = b2[321 + l];
    const float b2p = b2[320];

    int bslot[5];
    #pragma unroll
    for (int ks = 0; ks < 5; ++ks)
        bslot[ks] = ((ks * 2 + half) + 3 * ((l >> 3) & 3)) % 11;

    __syncthreads();

    for (int n = wave; n < 32; n += 4) {
        // ---- geometry: lane l = edge row rr ----
        const int rrc = (l < 31) ? l : 30;
        const int src = rrc + (rrc >= n ? 1 : 0);
        const float ax = sPosS[n][0],  ay = sPosS[n][1],  az = sPosS[n][2];
        const float bx = sPosS[src][0], by = sPosS[src][1], bz = sPosS[src][2];
        const float rx = ax - bx, ry = ay - by, rz = az - bz;
        const float av = ax * bx + ay * by + az * bz;
        const float dd = sqrtf(fmaxf(rx * rx + ry * ry + rz * rz, 1e-6f));
        const float inv = 1.f / (1.f + dd);
        if (half == 0) {
            const bool pad = (l == 31);
            sRn[wave][l][0] = pad ? 0.f : rx * inv;
            sRn[wave][l][1] = pad ? 0.f : ry * inv;
            sRn[wave][l][2] = pad ? 0.f : rz * inv;
        }
        // ---- A fragments ----
        const float* ebase = ebuf + ((size_t)((mol * 32 + n) * 31 + l)) * 32;
        bf16x8 fr0, fr1, fr2 = {}, fr3, fr4;
        {
            const float4 f0 = *(const float4*)(ebase + half * 8);
            const float4 f1 = *(const float4*)(ebase + half * 8 + 4);
            fr0[0]=bfc(f0.x); fr0[1]=bfc(f0.y); fr0[2]=bfc(f0.z); fr0[3]=bfc(f0.w);
            fr0[4]=bfc(f1.x); fr0[5]=bfc(f1.y); fr0[6]=bfc(f1.z); fr0[7]=bfc(f1.w);
            const float4 g0 = *(const float4*)(ebase + 16 + half * 8);
            const float4 g1 = *(const float4*)(ebase + 16 + half * 8 + 4);
            fr1[0]=bfc(g0.x); fr1[1]=bfc(g0.y); fr1[2]=bfc(g0.z); fr1[3]=bfc(g0.w);
            fr1[4]=bfc(g1.x); fr1[5]=bfc(g1.y); fr1[6]=bfc(g1.z); fr1[7]=bfc(g1.w);
        }
        if (half == 0) { fr2[0] = bfc(dd); fr2[1] = bfc(av); }
        #pragma unroll
        for (int jj = 0; jj < 8; ++jj) {
            fr3[jj] = (half * 8 + jj == src)      ? ONEBF : (short)0;
            fr4[jj] = (16 + half * 8 + jj == src) ? ONEBF : (short)0;
        }

        f32x16 accC = {};
        float pp[16];
        #pragma unroll
        for (int r = 0; r < 16; ++r) pp[r] = 0.f;
        float Hacc[8];

        const int g = l >> 3, jlow = l & 7;
        #pragma unroll
        for (int cb = 0; cb < 8; ++cb) {
            const float sbv = SB[(size_t)(node0 + n) * 256 + cb * 32 + l] + b1v[cb];
            f32x16 acc;
            #pragma unroll
            for (int r = 0; r < 16; ++r) acc[r] = sbv;
            {
                const short* brow = &sBg[cb * 32 + l][0];
                acc = __builtin_amdgcn_mfma_f32_32x32x16_bf16(fr0, *(const bf16x8*)(brow + bslot[0]*8), acc, 0,0,0);
                acc = __builtin_amdgcn_mfma_f32_32x32x16_bf16(fr1, *(const bf16x8*)(brow + bslot[1]*8), acc, 0,0,0);
                acc = __builtin_amdgcn_mfma_f32_32x32x16_bf16(fr2, *(const bf16x8*)(brow + bslot[2]*8), acc, 0,0,0);
                acc = __builtin_amdgcn_mfma_f32_32x32x16_bf16(fr3, *(const bf16x8*)(brow + bslot[3]*8), acc, 0,0,0);
                acc = __builtin_amdgcn_mfma_f32_32x32x16_bf16(fr4, *(const bf16x8*)(brow + bslot[4]*8), acc, 0,0,0);
            }
            float hs = 0.f;
            #pragma unroll
            for (int r = 0; r < 16; ++r) {
                const int e = (r & 3) + 8 * (r >> 2) + 4 * half;
                float h = silu_f(acc[r]);
                if (half == 1 && r == 15) h = 0.f;   // pad row 31
                hs += h;
                pp[r] += h * w2pv[cb];
                sHdn[wave][e][((g + (e >> 3)) & 3) * 8 + jlow] = bfc(h);
            }
            Hacc[cb] = hs;
            // phase C: consume this chunk (2 K-steps)
            #pragma unroll
            for (int q = 0; q < 2; ++q) {
                const int g2 = q * 2 + half;
                const bf16x8 afr = *(const bf16x8*)&sHdn[wave][l][((g2 + (l >> 3)) & 3) * 8];
                accC = __builtin_amdgcn_mfma_f32_32x32x16_bf16(afr, w2efr[cb * 2 + q], accC, 0,0,0);
            }
        }
        // ---- H ----
        #pragma unroll
        for (int cb = 0; cb < 8; ++cb) {
            const float v = Hacc[cb] + __shfl_xor(Hacc[cb], 32, 64);
            if (lane < 32) Hbuf[(size_t)(node0 + n) * 256 + cb * 32 + lane] = v;
        }
        // ---- p: butterfly over the 32 j-lanes of each half ----
        #pragma unroll
        for (int m = 1; m <= 16; m <<= 1) {
            #pragma unroll
            for (int r = 0; r < 16; ++r) pp[r] += __shfl_xor(pp[r], m, 64);
        }
        // ---- pd = sum rn * p ----
        float pd0 = 0.f, pd1 = 0.f, pd2 = 0.f;
        #pragma unroll
        for (int r = 0; r < 16; ++r) {
            const int e = (r & 3) + 8 * (r >> 2) + 4 * half;
            const float pfull = (half == 1 && r == 15) ? 0.f : (pp[r] + b2p);
            pd0 += sRn[wave][e][0] * pfull;
            pd1 += sRn[wave][e][1] * pfull;
            pd2 += sRn[wave][e][2] * pfull;
        }
        pd0 += __shfl_xor(pd0, 32, 64);
        pd1 += __shfl_xor(pd1, 32, 64);
        pd2 += __shfl_xor(pd2, 32, 64);
        if (lane == 0) {
            pdelta[(size_t)(node0 + n) * 3 + 0] = pd0;
            pdelta[(size_t)(node0 + n) * 3 + 1] = pd1;
            pdelta[(size_t)(node0 + n) * 3 + 2] = pd2;
        }
        // ---- e update ----
        #pragma unroll
        for (int r = 0; r < 16; ++r) {
            const int e = (r & 3) + 8 * (r >> 2) + 4 * half;
            if (e < 31) {
                float* ep = ebuf + ((size_t)((mol * 32 + n) * 31 + e)) * 32 + l;
                *ep = *ep + accC[r] + b2e;
            }
        }
    }
}

// ---------------------------------------------------------------------------
__global__ __launch_bounds__(256) void pos_update(float* __restrict__ pos,
                                                  const float* __restrict__ pd)
{
    const int i = blockIdx.x * 256 + threadIdx.x;
    pos[i] += pd[i] * (1.f / 31.f);
}

__global__ __launch_bounds__(256) void pos_copy(const float* __restrict__ pos,
                                                float* __restrict__ out)
{
    const int i = blockIdx.x * 256 + threadIdx.x;
    out[i] = pos[i];
}

// ---------------------------------------------------------------------------
__global__ __launch_bounds__(256) void atoms_kernel(
    const float* __restrict__ tmp, const float* __restrict__ Wh2,
    const float* __restrict__ bh2, float* __restrict__ outA)
{
    const int gid = blockIdx.x * 256 + threadIdx.x;
    const int n = gid >> 4, o = gid & 15;
    float acc = bh2[o];
    #pragma unroll 8
    for (int k = 0; k < SDIM_; ++k) acc += tmp[(size_t)n * SDIM_ + k] * Wh2[k * NAF_ + o];
    outA[gid] = acc;
}

// ---------------------------------------------------------------------------
// bond head, tgt-major e layout. Block per molecule.
// ---------------------------------------------------------------------------
__global__ __launch_bounds__(256) void bond_kernel2(
    const float* __restrict__ U, const float* __restrict__ pos,
    const float* __restrict__ ebuf, const float* __restrict__ We1,
    const float* __restrict__ be1, const float* __restrict__ We2,
    const float* __restrict__ be2, float* __restrict__ outB)
{
    const int mol = blockIdx.x, t = threadIdx.x;
    const int node0 = mol * 32;
    __shared__ float sU[32][132];
    __shared__ float sHb[32][132];
    __shared__ float sEb[32][33];
    __shared__ float sW25T[5][132];
    __shared__ float sPos[32][4];
    __shared__ float sD[32];

    for (int i = t; i < 32 * 128; i += 256) sU[i >> 7][i & 127] = U[(size_t)node0 * 128 + i];
    for (int i = t; i < 5 * 128; i += 256) sW25T[i >> 7][i & 127] = We2[(i & 127) * 5 + (i >> 7)];
    if (t < 96) sPos[t / 3][t % 3] = pos[node0 * 3 + t];

    const int j = t & 127;
    float we1e[32];
    #pragma unroll
    for (int k = 0; k < 32; ++k) we1e[k] = We1[(size_t)(256 + k) * 128 + j];
    const float we1d = We1[(size_t)288 * 128 + j];
    const float be1j = be1[j];
    __syncthreads();

    for (int n = 0; n < 32; ++n) {
        for (int i = t; i < 31 * 32; i += 256)
            ((float*)sEb)[(i >> 5) * 33 + (i & 31)] = ebuf[(size_t)((mol * 32 + n) * 31) * 32 + i];
        if (t < 32) {
            const int rrc = (t < 31) ? t : 30;
            const int s_ = rrc + (rrc >= n ? 1 : 0);
            const float rx = sPos[n][0] - sPos[s_][0];
            const float ry = sPos[n][1] - sPos[s_][1];
            const float rz = sPos[n][2] - sPos[s_][2];
            sD[t] = sqrtf(fmaxf(rx * rx + ry * ry + rz * rz, 1e-6f));
        }
        __syncthreads();
        for (int rr = (t >> 7); rr < 31; rr += 2) {
            const int s_ = rr + (rr >= n ? 1 : 0);
            float acc = be1j + sU[s_][j] + sU[n][j] + sD[rr] * we1d;
            #pragma unroll
            for (int k = 0; k < 32; ++k) acc += sEb[rr][k] * we1e[k];
            sHb[rr][j] = silu_f(acc);
        }
        __syncthreads();
        if (t < 155) {
            const int rr = t / 5, o = t - 5 * (t / 5);
            const int s_ = rr + (rr >= n ? 1 : 0);
            float acc = be2[o];
            #pragma unroll 8
            for (int k = 0; k < 128; k += 4) {
                acc += sHb[rr][k] * sW25T[o][k] + sHb[rr][k + 1] * sW25T[o][k + 1]
                     + sHb[rr][k + 2] * sW25T[o][k + 2] + sHb[rr][k + 3] * sW25T[o][k + 3];
            }
            const int ge = (mol * 32 + s_) * 31 + (n - (n > s_ ? 1 : 0));
            outB[(size_t)ge * 5 + o] = acc;
        }
        __syncthreads();
    }
}

// ---------------------------------------------------------------------------
extern "C" void kernel_launch(void* const* d_in, const int* in_sizes, int n_in,
                              void* d_out, int out_size, void* d_ws, size_t ws_size,
                              hipStream_t stream) {
    const float* x   = (const float*)d_in[0];
    const float* z   = (const float*)d_in[1];
    const float* rot = (const float*)d_in[2];
    const float* ea  = (const float*)d_in[4];
    const float* Wam = (const float*)d_in[6];
    const float* bam = (const float*)d_in[7];
    const float* Wbm = (const float*)d_in[8];
    const float* bbm = (const float*)d_in[9];
    const float* gW1 = (const float*)d_in[10];
    const float* gb1 = (const float*)d_in[11];
    const float* gW2 = (const float*)d_in[12];
    const float* gb2 = (const float*)d_in[13];
    const float* Wh1 = (const float*)d_in[14];
    const float* bh1 = (const float*)d_in[15];
    const float* Wh2 = (const float*)d_in[16];
    const float* bh2 = (const float*)d_in[17];
    const float* We1 = (const float*)d_in[18];
    const float* be1 = (const float*)d_in[19];
    const float* We2 = (const float*)d_in[20];
    const float* be2 = (const float*)d_in[21];
    float* out = (float*)d_out;

    float* ws  = (float*)d_ws;
    float* s   = ws;                    // 8192*256        = 2097152
    float* pos = ws + 2097152;          // 8192*3          = 24576
    float* e   = ws + 2121728;          // 8192*31*32      = 8126464
    float* SA  = ws + 10248192;         // 8192*256
    float* SB  = ws + 12345344;         // 8192*256
    float* H   = ws + 14442496;         // 8192*256
    float* pd  = ws + 16539648;         // 8192*3
    float* tmp = SA;
    float* U   = H;

    node_init<<<NN, 256, 0, stream>>>(x, z, rot, Wam, bam, s, pos);
    edge_init2<<<NN, 256, 0, stream>>>(ea, Wbm, bbm, e);

    for (int l = 0; l < LAYERS_; ++l) {
        const float* W1 = gW1 + (size_t)l * 546 * 256;
        const float* b1 = gb1 + l * 256;
        const float* W2 = gW2 + (size_t)l * 256 * 353;
        const float* b2 = gb2 + l * 353;
        gemm64<0,0><<<dim3(4, 128), 256, 0, stream>>>(s, W1,             SA, nullptr, 256, 256, 256, 1.f);
        gemm64<0,0><<<dim3(4, 128), 256, 0, stream>>>(s, W1 + 256 * 256, SB, nullptr, 256, 256, 256, 1.f);
        edge_mfma<<<N_MOLS, 256, 0, stream>>>(SA, SB, pos, e, W1, b1, W2, b2, H, pd);
        gemm64<0,1><<<dim3(4, 128), 256, 0, stream>>>(H, W2, s, b2, 256, 256, 353, 1.f / 31.f);
        pos_update<<<96, 256, 0, stream>>>(pos, pd);
    }

    gemm64<1,0><<<dim3(4, 128), 256, 0, stream>>>(s, Wh1, tmp, bh1, 256, 256, 256, 1.f);
    atoms_kernel<<<512, 256, 0, stream>>>(tmp, Wh2, bh2, out);

    gemm64<0,0><<<dim3(2, 128), 256, 0, stream>>>(s, We1, U, nullptr, 256, 128, 128, 1.f);
    bond_kernel2<<<N_MOLS, 256, 0, stream>>>(U, pos, e, We1, be1, We2, be2, out + 131072);

    pos_copy<<<96, 256, 0, stream>>>(pos, out + 131072 + 1269760);
}

// Round 3
// 961.673 us; speedup vs baseline: 3.8766x; 1.4671x over previous
//
#include <hip/hip_runtime.h>
#include <hip/hip_bf16.h>
#include <cstdint>
#include <cstddef>

#define N_MOLS 256
#define N_PER  32
#define NN     8192
#define EDGES  253952
#define SDIM_  256
#define EDIM_  32
#define NAF_   16
#define LAYERS_ 5

typedef __attribute__((ext_vector_type(8)))  short bf16x8;
typedef __attribute__((ext_vector_type(16))) float f32x16;

__device__ __forceinline__ float silu_f(float x) {
    return x / (1.f + __expf(-x));
}
__device__ __forceinline__ short bfc(float f) {
    __hip_bfloat16 h = __float2bfloat16(f);
    return __builtin_bit_cast(short, h);
}
#define ONEBF ((short)0x3F80)

// ---------------------------------------------------------------------------
// node init: h = [x|z]@Wam+bam; s = h[:,:256]; pos = rot[mol]@h[:,256:259]
// ---------------------------------------------------------------------------
__global__ __launch_bounds__(256) void node_init(
    const float* __restrict__ x, const float* __restrict__ z,
    const float* __restrict__ rot, const float* __restrict__ Wam,
    const float* __restrict__ bam, float* __restrict__ s, float* __restrict__ pos)
{
    const int n = blockIdx.x, t = threadIdx.x;
    __shared__ float xz[80];
    __shared__ float praw[3];
    if (t < 16)      xz[t] = x[n * 16 + t];
    else if (t < 80) xz[t] = z[n * 64 + (t - 16)];
    __syncthreads();
    float acc = bam[t];
    #pragma unroll 8
    for (int k = 0; k < 80; ++k) acc += xz[k] * Wam[k * 259 + t];
    s[(size_t)n * SDIM_ + t] = acc;
    if (t < 3) {
        const int j2 = 256 + t;
        float a2 = bam[j2];
        for (int k = 0; k < 80; ++k) a2 += xz[k] * Wam[k * 259 + j2];
        praw[t] = a2;
    }
    __syncthreads();
    if (t < 3) {
        const int mol = n >> 5;
        float p = 0.f;
        for (int jj = 0; jj < 3; ++jj) p += rot[mol * 9 + t * 3 + jj] * praw[jj];
        pos[n * 3 + t] = p;
    }
}

// ---------------------------------------------------------------------------
// edge feature init into tgt-major layout: e[((mol*32+n)*31+rr)*32+c]
// ---------------------------------------------------------------------------
__global__ __launch_bounds__(256) void edge_init2(
    const float* __restrict__ ea, const float* __restrict__ Wbm,
    const float* __restrict__ bbm, float* __restrict__ ebuf)
{
    const int tile = blockIdx.x;          // mol*32 + n
    const int mol = tile >> 5, n = tile & 31;
    const int t = threadIdx.x;
    for (int i = t; i < 31 * 32; i += 256) {
        const int rr = i >> 5, c = i & 31;
        const int s_ = rr + (rr >= n ? 1 : 0);
        const int ge = (mol * 32 + s_) * 31 + (n - (n > s_ ? 1 : 0));
        float acc = bbm[c];
        #pragma unroll
        for (int k = 0; k < 5; ++k) acc += ea[(size_t)ge * 5 + k] * Wbm[k * 32 + c];
        ebuf[(size_t)tile * 31 * 32 + i] = acc;
    }
}

// ---------------------------------------------------------------------------
// bf16 MFMA GEMM: C[M,N] = act(alpha*(A@B) + bias) (+= if ACCUM)
// A fp32 [M,K]; B fp32 rows with stride ldb; tile 128M x 64N, 256 thr (4 waves)
// wave (wm,wn): rows m0+wm*64..+63, cols n0+wn*32..+31. K % 32 == 0.
// ---------------------------------------------------------------------------
template<int ACT, int ACCUM>
__global__ __launch_bounds__(256) void gemm_mfma(
    const float* __restrict__ A, const float* __restrict__ B,
    float* __restrict__ C, const float* __restrict__ bias,
    int K, int N, int ldb, float alpha)
{
    const int n0 = blockIdx.x * 64, m0 = blockIdx.y * 128;
    const int t = threadIdx.x;
    const int wave = t >> 6, lane = t & 63;
    const int l = lane & 31, half = lane >> 5;
    const int wm = wave & 1, wn = wave >> 1;
    __shared__ __align__(16) short sA[128][40];
    __shared__ __align__(16) short sBt[64][40];
    f32x16 acc0 = {}, acc1 = {};
    const int mA = t >> 1, koA = (t & 1) * 16;
    const int krB = t >> 3, ncB = (t & 7) * 8;
    for (int k0 = 0; k0 < K; k0 += 32) {
        {   // stage A tile 128x32 as bf16
            const float* ap = A + (size_t)(m0 + mA) * K + k0 + koA;
            const float4 a0 = *(const float4*)(ap);
            const float4 a1 = *(const float4*)(ap + 4);
            const float4 a2 = *(const float4*)(ap + 8);
            const float4 a3 = *(const float4*)(ap + 12);
            bf16x8 p0, p1;
            p0[0]=bfc(a0.x); p0[1]=bfc(a0.y); p0[2]=bfc(a0.z); p0[3]=bfc(a0.w);
            p0[4]=bfc(a1.x); p0[5]=bfc(a1.y); p0[6]=bfc(a1.z); p0[7]=bfc(a1.w);
            p1[0]=bfc(a2.x); p1[1]=bfc(a2.y); p1[2]=bfc(a2.z); p1[3]=bfc(a2.w);
            p1[4]=bfc(a3.x); p1[5]=bfc(a3.y); p1[6]=bfc(a3.z); p1[7]=bfc(a3.w);
            *(bf16x8*)&sA[mA][koA]     = p0;
            *(bf16x8*)&sA[mA][koA + 8] = p1;
        }
        {   // stage B tile 32x64 transposed
            const float* bp = B + (size_t)(k0 + krB) * ldb + n0 + ncB;
            const float4 b0 = *(const float4*)(bp);
            const float4 b1_ = *(const float4*)(bp + 4);
            sBt[ncB + 0][krB] = bfc(b0.x);  sBt[ncB + 1][krB] = bfc(b0.y);
            sBt[ncB + 2][krB] = bfc(b0.z);  sBt[ncB + 3][krB] = bfc(b0.w);
            sBt[ncB + 4][krB] = bfc(b1_.x); sBt[ncB + 5][krB] = bfc(b1_.y);
            sBt[ncB + 6][krB] = bfc(b1_.z); sBt[ncB + 7][krB] = bfc(b1_.w);
        }
        __syncthreads();
        #pragma unroll
        for (int ks = 0; ks < 2; ++ks) {
            const bf16x8 bfrag = *(const bf16x8*)&sBt[wn * 32 + l][ks * 16 + half * 8];
            const bf16x8 afr0  = *(const bf16x8*)&sA[wm * 64 + l][ks * 16 + half * 8];
            const bf16x8 afr1  = *(const bf16x8*)&sA[wm * 64 + 32 + l][ks * 16 + half * 8];
            acc0 = __builtin_amdgcn_mfma_f32_32x32x16_bf16(afr0, bfrag, acc0, 0,0,0);
            acc1 = __builtin_amdgcn_mfma_f32_32x32x16_bf16(afr1, bfrag, acc1, 0,0,0);
        }
        __syncthreads();
    }
    const int n = n0 + wn * 32 + l;
    const float bv = bias ? bias[n] : 0.f;
    #pragma unroll
    for (int r = 0; r < 16; ++r) {
        const int row = (r & 3) + 8 * (r >> 2) + 4 * half;
        {
            const int m = m0 + wm * 64 + row;
            float v = alpha * acc0[r] + bv;
            if (ACT) v = silu_f(v);
            if (ACCUM) C[(size_t)m * N + n] += v; else C[(size_t)m * N + n] = v;
        }
        {
            const int m = m0 + wm * 64 + 32 + row;
            float v = alpha * acc1[r] + bv;
            if (ACT) v = silu_f(v);
            if (ACCUM) C[(size_t)m * N + n] += v; else C[(size_t)m * N + n] = v;
        }
    }
}

// ---------------------------------------------------------------------------
// MFMA edge kernel v2. Grid 512 (2 blocks/mol), 512 thr (8 waves).
// Block handles tgt nodes n in [nbase, nbase+16); wave w: n = nbase+w, +8.
// sBg k-layout: k0..31 = e-weights W1c, k32..63 = SA rows (onehot gather);
// d/a handled as a register-built B fragment.
// ---------------------------------------------------------------------------
__global__ __launch_bounds__(512) void edge_mfma(
    const float* __restrict__ SA, const float* __restrict__ SB,
    const float* __restrict__ pos, float* __restrict__ ebuf,
    const float* __restrict__ W1, const float* __restrict__ b1,
    const float* __restrict__ W2, const float* __restrict__ b2,
    float* __restrict__ Hbuf, float* __restrict__ pdelta)
{
    const int blk = blockIdx.x;
    const int mol = blk >> 1;
    const int nbase = (blk & 1) * 16;
    const int t = threadIdx.x;
    const int wave = t >> 6, lane = t & 63;
    const int l = lane & 31, half = lane >> 5;
    const int node0 = mol * 32;

    __shared__ __align__(16) short sBg[256][72];    // 36 KB, 9 slots x 8
    __shared__ __align__(16) short sHdn[8][32][40]; // 20 KB (also W2e staging)
    __shared__ float sPosS[32][4];
    __shared__ float sRn[8][32][4];
    __shared__ short sW1da[2][256];

    {   // stage sBg
        const int j = t & 255;
        const int k0s = (t >> 8) * 32;
        for (int kk = 0; kk < 32; ++kk) {
            const int k = k0s + kk;
            const float v = (k < 32) ? W1[(size_t)(512 + k) * 256 + j]
                                     : SA[(size_t)(node0 + (k - 32)) * 256 + j];
            const int slot = ((k >> 3) + 3 * ((j >> 3) & 3)) & 7;
            sBg[j][slot * 8 + (k & 7)] = bfc(v);
        }
    }
    if (t < 256) {
        sW1da[0][t] = bfc(W1[(size_t)544 * 256 + t]);
        sW1da[1][t] = bfc(W1[(size_t)545 * 256 + t]);
    }
    if (t < 96) sPosS[t / 3][t % 3] = pos[node0 * 3 + t];

    // stage W2e cols 321..352 into sHdn-aliased scratch (coalesced), then frags
    short* sW2e = &sHdn[0][0][0];   // needs 8192 shorts <= 10240 avail
    for (int i = 0; i < 16; ++i) {
        const int gi = i * 512 + t;
        const int c = gi & 31, j = gi >> 5;
        const int kk = j >> 4, hw = (j >> 3) & 1, jj = j & 7;
        sW2e[(size_t)(kk * 64 + hw * 32 + c) * 8 + jj] = bfc(W2[(size_t)j * 353 + 321 + c]);
    }
    __syncthreads();
    bf16x8 w2efr[16];
    #pragma unroll
    for (int kk = 0; kk < 16; ++kk)
        w2efr[kk] = *(const bf16x8*)&sW2e[(size_t)(kk * 64 + lane) * 8];
    float w2pv[8], b1v[8];
    short w1dv[8], w1av[8];
    #pragma unroll
    for (int cb = 0; cb < 8; ++cb) {
        w2pv[cb] = W2[(size_t)(cb * 32 + l) * 353 + 320];
        b1v[cb]  = b1[cb * 32 + l];
        w1dv[cb] = sW1da[0][cb * 32 + l];
        w1av[cb] = sW1da[1][cb * 32 + l];
    }
    const float b2e = b2[321 + l];
    const float b2p = b2[320];
    int bslot[4];
    #pragma unroll
    for (int ks = 0; ks < 4; ++ks)
        bslot[ks] = ((ks * 2 + half) + 3 * ((l >> 3) & 3)) & 7;
    __syncthreads();   // all waves done reading sW2e before sHdn reuse

    for (int ni = 0; ni < 2; ++ni) {
        const int n = nbase + wave + ni * 8;
        // geometry: lane l = edge row rr
        const int rrc = (l < 31) ? l : 30;
        const int src = rrc + (rrc >= n ? 1 : 0);
        const float ax = sPosS[n][0],  ay = sPosS[n][1],  az = sPosS[n][2];
        const float bx = sPosS[src][0], by = sPosS[src][1], bz = sPosS[src][2];
        const float rx = ax - bx, ry = ay - by, rz = az - bz;
        const float av = ax * bx + ay * by + az * bz;
        const float dd = sqrtf(fmaxf(rx * rx + ry * ry + rz * rz, 1e-6f));
        const float inv = 1.f / (1.f + dd);
        if (half == 0) {
            const bool pad = (l == 31);
            sRn[wave][l][0] = pad ? 0.f : rx * inv;
            sRn[wave][l][1] = pad ? 0.f : ry * inv;
            sRn[wave][l][2] = pad ? 0.f : rz * inv;
        }
        // A fragments
        const float* ebase = ebuf + ((size_t)((mol * 32 + n) * 31 + l)) * 32;
        bf16x8 fr0, fr1, fr2 = {}, fr3, fr4;
        {
            const float4 f0 = *(const float4*)(ebase + half * 8);
            const float4 f1 = *(const float4*)(ebase + half * 8 + 4);
            fr0[0]=bfc(f0.x); fr0[1]=bfc(f0.y); fr0[2]=bfc(f0.z); fr0[3]=bfc(f0.w);
            fr0[4]=bfc(f1.x); fr0[5]=bfc(f1.y); fr0[6]=bfc(f1.z); fr0[7]=bfc(f1.w);
            const float4 g0 = *(const float4*)(ebase + 16 + half * 8);
            const float4 g1 = *(const float4*)(ebase + 16 + half * 8 + 4);
            fr1[0]=bfc(g0.x); fr1[1]=bfc(g0.y); fr1[2]=bfc(g0.z); fr1[3]=bfc(g0.w);
            fr1[4]=bfc(g1.x); fr1[5]=bfc(g1.y); fr1[6]=bfc(g1.z); fr1[7]=bfc(g1.w);
        }
        if (half == 0) { fr2[0] = bfc(dd); fr2[1] = bfc(av); }
        #pragma unroll
        for (int jj = 0; jj < 8; ++jj) {
            fr3[jj] = (half * 8 + jj == src)      ? ONEBF : (short)0;
            fr4[jj] = (16 + half * 8 + jj == src) ? ONEBF : (short)0;
        }

        f32x16 accC = {};
        float pp[16];
        #pragma unroll
        for (int r = 0; r < 16; ++r) pp[r] = 0.f;
        float Hacc[8];

        const int g = l >> 3, jlow = l & 7;
        #pragma unroll
        for (int cb = 0; cb < 8; ++cb) {
            const float sbv = SB[(size_t)(node0 + n) * 256 + cb * 32 + l] + b1v[cb];
            f32x16 acc;
            #pragma unroll
            for (int r = 0; r < 16; ++r) acc[r] = sbv;
            {
                const short* brow = &sBg[cb * 32 + l][0];
                acc = __builtin_amdgcn_mfma_f32_32x32x16_bf16(fr0, *(const bf16x8*)(brow + bslot[0]*8), acc, 0,0,0);
                acc = __builtin_amdgcn_mfma_f32_32x32x16_bf16(fr1, *(const bf16x8*)(brow + bslot[1]*8), acc, 0,0,0);
                acc = __builtin_amdgcn_mfma_f32_32x32x16_bf16(fr3, *(const bf16x8*)(brow + bslot[2]*8), acc, 0,0,0);
                acc = __builtin_amdgcn_mfma_f32_32x32x16_bf16(fr4, *(const bf16x8*)(brow + bslot[3]*8), acc, 0,0,0);
                bf16x8 frB2 = {};
                if (half == 0) { frB2[0] = w1dv[cb]; frB2[1] = w1av[cb]; }
                acc = __builtin_amdgcn_mfma_f32_32x32x16_bf16(fr2, frB2, acc, 0,0,0);
            }
            float hs = 0.f;
            #pragma unroll
            for (int r = 0; r < 16; ++r) {
                const int e = (r & 3) + 8 * (r >> 2) + 4 * half;
                float h = silu_f(acc[r]);
                if (half == 1 && r == 15) h = 0.f;   // pad row 31
                hs += h;
                pp[r] += h * w2pv[cb];
                sHdn[wave][e][((g + (e >> 3)) & 3) * 8 + jlow] = bfc(h);
            }
            Hacc[cb] = hs;
            #pragma unroll
            for (int q = 0; q < 2; ++q) {
                const int g2 = q * 2 + half;
                const bf16x8 afr = *(const bf16x8*)&sHdn[wave][l][((g2 + (l >> 3)) & 3) * 8];
                accC = __builtin_amdgcn_mfma_f32_32x32x16_bf16(afr, w2efr[cb * 2 + q], accC, 0,0,0);
            }
        }
        // H
        #pragma unroll
        for (int cb = 0; cb < 8; ++cb) {
            const float v = Hacc[cb] + __shfl_xor(Hacc[cb], 32, 64);
            if (lane < 32) Hbuf[(size_t)(node0 + n) * 256 + cb * 32 + lane] = v;
        }
        // p butterfly over 32 j-lanes per half
        #pragma unroll
        for (int m = 1; m <= 16; m <<= 1) {
            #pragma unroll
            for (int r = 0; r < 16; ++r) pp[r] += __shfl_xor(pp[r], m, 64);
        }
        // pd = sum rn * p
        float pd0 = 0.f, pd1 = 0.f, pd2 = 0.f;
        #pragma unroll
        for (int r = 0; r < 16; ++r) {
            const int e = (r & 3) + 8 * (r >> 2) + 4 * half;
            const float pfull = (half == 1 && r == 15) ? 0.f : (pp[r] + b2p);
            pd0 += sRn[wave][e][0] * pfull;
            pd1 += sRn[wave][e][1] * pfull;
            pd2 += sRn[wave][e][2] * pfull;
        }
        pd0 += __shfl_xor(pd0, 32, 64);
        pd1 += __shfl_xor(pd1, 32, 64);
        pd2 += __shfl_xor(pd2, 32, 64);
        if (lane == 0) {
            pdelta[(size_t)(node0 + n) * 3 + 0] = pd0;
            pdelta[(size_t)(node0 + n) * 3 + 1] = pd1;
            pdelta[(size_t)(node0 + n) * 3 + 2] = pd2;
        }
        // e update
        #pragma unroll
        for (int r = 0; r < 16; ++r) {
            const int e = (r & 3) + 8 * (r >> 2) + 4 * half;
            if (e < 31) {
                float* ep = ebuf + ((size_t)((mol * 32 + n) * 31 + e)) * 32 + l;
                *ep = *ep + accC[r] + b2e;
            }
        }
    }
}

// ---------------------------------------------------------------------------
// MFMA bond kernel. Grid 512 (2 blocks/mol), 512 thr (8 waves).
// pre[32e][128] = Ageo[32][64] @ [We1e;U] + (U[n][j] + be1[j]); d via reg frag.
// bonds[e][5] = silu(pre) @ We2 (+be2) via padded 32-col MFMA.
// ---------------------------------------------------------------------------
__global__ __launch_bounds__(512) void bond_mfma(
    const float* __restrict__ U, const float* __restrict__ pos,
    const float* __restrict__ ebuf, const float* __restrict__ We1,
    const float* __restrict__ be1, const float* __restrict__ We2,
    const float* __restrict__ be2, float* __restrict__ outB)
{
    const int blk = blockIdx.x;
    const int mol = blk >> 1;
    const int nbase = (blk & 1) * 16;
    const int t = threadIdx.x;
    const int wave = t >> 6, lane = t & 63;
    const int l = lane & 31, half = lane >> 5;
    const int node0 = mol * 32;

    __shared__ __align__(16) short sBg2[128][72];
    __shared__ __align__(16) short sHdnB[8][32][40];
    __shared__ float sPosS[32][4];
    __shared__ short sWd[128];

    {   // stage sBg2: j = t & 127, kq = t >> 7 -> k = kq*16..+15
        const int j = t & 127, kq = t >> 7;
        for (int kk = 0; kk < 16; ++kk) {
            const int k = kq * 16 + kk;
            const float v = (k < 32) ? We1[(size_t)(256 + k) * 128 + j]
                                     : U[(size_t)(node0 + (k - 32)) * 128 + j];
            const int slot = ((k >> 3) + 3 * ((j >> 3) & 3)) & 7;
            sBg2[j][slot * 8 + (k & 7)] = bfc(v);
        }
    }
    if (t < 128) sWd[t] = bfc(We1[(size_t)288 * 128 + t]);
    if (t < 96) sPosS[t / 3][t % 3] = pos[node0 * 3 + t];

    bf16x8 w2fr[8];
    #pragma unroll
    for (int kk = 0; kk < 8; ++kk) {
        #pragma unroll
        for (int jj = 0; jj < 8; ++jj) {
            const int k = kk * 16 + half * 8 + jj;
            w2fr[kk][jj] = (l < 5) ? bfc(We2[(size_t)k * 5 + l]) : (short)0;
        }
    }
    float be1v[4];
    #pragma unroll
    for (int cb = 0; cb < 4; ++cb) be1v[cb] = be1[cb * 32 + l];
    const float be2v = (l < 5) ? be2[l] : 0.f;
    int bslot[4];
    #pragma unroll
    for (int ks = 0; ks < 4; ++ks)
        bslot[ks] = ((ks * 2 + half) + 3 * ((l >> 3) & 3)) & 7;
    __syncthreads();

    for (int ni = 0; ni < 2; ++ni) {
        const int n = nbase + wave + ni * 8;
        const int rrc = (l < 31) ? l : 30;
        const int src = rrc + (rrc >= n ? 1 : 0);
        const float rx = sPosS[n][0] - sPosS[src][0];
        const float ry = sPosS[n][1] - sPosS[src][1];
        const float rz = sPosS[n][2] - sPosS[src][2];
        const float dd = sqrtf(fmaxf(rx * rx + ry * ry + rz * rz, 1e-6f));

        const float* ebase = ebuf + ((size_t)((mol * 32 + n) * 31 + l)) * 32;
        bf16x8 fr0, fr1, fr2 = {}, fr3, fr4;
        {
            const float4 f0 = *(const float4*)(ebase + half * 8);
            const float4 f1 = *(const float4*)(ebase + half * 8 + 4);
            fr0[0]=bfc(f0.x); fr0[1]=bfc(f0.y); fr0[2]=bfc(f0.z); fr0[3]=bfc(f0.w);
            fr0[4]=bfc(f1.x); fr0[5]=bfc(f1.y); fr0[6]=bfc(f1.z); fr0[7]=bfc(f1.w);
            const float4 g0 = *(const float4*)(ebase + 16 + half * 8);
            const float4 g1 = *(const float4*)(ebase + 16 + half * 8 + 4);
            fr1[0]=bfc(g0.x); fr1[1]=bfc(g0.y); fr1[2]=bfc(g0.z); fr1[3]=bfc(g0.w);
            fr1[4]=bfc(g1.x); fr1[5]=bfc(g1.y); fr1[6]=bfc(g1.z); fr1[7]=bfc(g1.w);
        }
        if (half == 0) fr2[0] = bfc(dd);
        #pragma unroll
        for (int jj = 0; jj < 8; ++jj) {
            fr3[jj] = (half * 8 + jj == src)      ? ONEBF : (short)0;
            fr4[jj] = (16 + half * 8 + jj == src) ? ONEBF : (short)0;
        }

        f32x16 accC = {};
        const int g = l >> 3, jlow = l & 7;
        #pragma unroll
        for (int cb = 0; cb < 4; ++cb) {
            const float uin = U[(size_t)(node0 + n) * 128 + cb * 32 + l] + be1v[cb];
            f32x16 acc;
            #pragma unroll
            for (int r = 0; r < 16; ++r) acc[r] = uin;
            {
                const short* brow = &sBg2[cb * 32 + l][0];
                acc = __builtin_amdgcn_mfma_f32_32x32x16_bf16(fr0, *(const bf16x8*)(brow + bslot[0]*8), acc, 0,0,0);
                acc = __builtin_amdgcn_mfma_f32_32x32x16_bf16(fr1, *(const bf16x8*)(brow + bslot[1]*8), acc, 0,0,0);
                acc = __builtin_amdgcn_mfma_f32_32x32x16_bf16(fr3, *(const bf16x8*)(brow + bslot[2]*8), acc, 0,0,0);
                acc = __builtin_amdgcn_mfma_f32_32x32x16_bf16(fr4, *(const bf16x8*)(brow + bslot[3]*8), acc, 0,0,0);
                bf16x8 frWd = {};
                if (half == 0) frWd[0] = sWd[cb * 32 + l];
                acc = __builtin_amdgcn_mfma_f32_32x32x16_bf16(fr2, frWd, acc, 0,0,0);
            }
            #pragma unroll
            for (int r = 0; r < 16; ++r) {
                const int e = (r & 3) + 8 * (r >> 2) + 4 * half;
                sHdnB[wave][e][((g + (e >> 3)) & 3) * 8 + jlow] = bfc(silu_f(acc[r]));
            }
            #pragma unroll
            for (int q = 0; q < 2; ++q) {
                const int g2 = q * 2 + half;
                const bf16x8 afr = *(const bf16x8*)&sHdnB[wave][l][((g2 + (l >> 3)) & 3) * 8];
                accC = __builtin_amdgcn_mfma_f32_32x32x16_bf16(afr, w2fr[cb * 2 + q], accC, 0,0,0);
            }
        }
        if (l < 5) {
            #pragma unroll
            for (int r = 0; r < 16; ++r) {
                const int e = (r & 3) + 8 * (r >> 2) + 4 * half;
                if (e < 31) {
                    const int s_ = e + (e >= n ? 1 : 0);
                    const int ge = (mol * 32 + s_) * 31 + (n - (n > s_ ? 1 : 0));
                    outB[(size_t)ge * 5 + l] = accC[r] + be2v;
                }
            }
        }
    }
}

// ---------------------------------------------------------------------------
__global__ __launch_bounds__(256) void pos_update(float* __restrict__ pos,
                                                  const float* __restrict__ pd)
{
    const int i = blockIdx.x * 256 + threadIdx.x;
    pos[i] += pd[i] * (1.f / 31.f);
}

__global__ __launch_bounds__(256) void pos_copy(const float* __restrict__ pos,
                                                float* __restrict__ out)
{
    const int i = blockIdx.x * 256 + threadIdx.x;
    out[i] = pos[i];
}

// ---------------------------------------------------------------------------
__global__ __launch_bounds__(256) void atoms_kernel(
    const float* __restrict__ tmp, const float* __restrict__ Wh2,
    const float* __restrict__ bh2, float* __restrict__ outA)
{
    const int gid = blockIdx.x * 256 + threadIdx.x;
    const int n = gid >> 4, o = gid & 15;
    float acc = bh2[o];
    #pragma unroll 8
    for (int k = 0; k < SDIM_; ++k) acc += tmp[(size_t)n * SDIM_ + k] * Wh2[k * NAF_ + o];
    outA[gid] = acc;
}

// ---------------------------------------------------------------------------
extern "C" void kernel_launch(void* const* d_in, const int* in_sizes, int n_in,
                              void* d_out, int out_size, void* d_ws, size_t ws_size,
                              hipStream_t stream) {
    const float* x   = (const float*)d_in[0];
    const float* z   = (const float*)d_in[1];
    const float* rot = (const float*)d_in[2];
    const float* ea  = (const float*)d_in[4];
    const float* Wam = (const float*)d_in[6];
    const float* bam = (const float*)d_in[7];
    const float* Wbm = (const float*)d_in[8];
    const float* bbm = (const float*)d_in[9];
    const float* gW1 = (const float*)d_in[10];
    const float* gb1 = (const float*)d_in[11];
    const float* gW2 = (const float*)d_in[12];
    const float* gb2 = (const float*)d_in[13];
    const float* Wh1 = (const float*)d_in[14];
    const float* bh1 = (const float*)d_in[15];
    const float* Wh2 = (const float*)d_in[16];
    const float* bh2 = (const float*)d_in[17];
    const float* We1 = (const float*)d_in[18];
    const float* be1 = (const float*)d_in[19];
    const float* We2 = (const float*)d_in[20];
    const float* be2 = (const float*)d_in[21];
    float* out = (float*)d_out;

    float* ws  = (float*)d_ws;
    float* s   = ws;                    // 8192*256
    float* pos = ws + 2097152;          // 8192*3
    float* e   = ws + 2121728;          // 8192*31*32
    float* SA  = ws + 10248192;         // 8192*256
    float* SB  = ws + 12345344;         // 8192*256
    float* H   = ws + 14442496;         // 8192*256
    float* pd  = ws + 16539648;         // 8192*3
    float* tmp = SA;
    float* U   = H;

    node_init<<<NN, 256, 0, stream>>>(x, z, rot, Wam, bam, s, pos);
    edge_init2<<<NN, 256, 0, stream>>>(ea, Wbm, bbm, e);

    for (int l = 0; l < LAYERS_; ++l) {
        const float* W1 = gW1 + (size_t)l * 546 * 256;
        const float* b1 = gb1 + l * 256;
        const float* W2 = gW2 + (size_t)l * 256 * 353;
        const float* b2 = gb2 + l * 353;
        gemm_mfma<0,0><<<dim3(4, 64), 256, 0, stream>>>(s, W1,             SA, nullptr, 256, 256, 256, 1.f);
        gemm_mfma<0,0><<<dim3(4, 64), 256, 0, stream>>>(s, W1 + 256 * 256, SB, nullptr, 256, 256, 256, 1.f);
        edge_mfma<<<2 * N_MOLS, 512, 0, stream>>>(SA, SB, pos, e, W1, b1, W2, b2, H, pd);
        gemm_mfma<0,1><<<dim3(4, 64), 256, 0, stream>>>(H, W2, s, b2, 256, 256, 353, 1.f / 31.f);
        pos_update<<<96, 256, 0, stream>>>(pos, pd);
    }

    gemm_mfma<1,0><<<dim3(4, 64), 256, 0, stream>>>(s, Wh1, tmp, bh1, 256, 256, 256, 1.f);
    atoms_kernel<<<512, 256, 0, stream>>>(tmp, Wh2, bh2, out);

    gemm_mfma<0,0><<<dim3(2, 64), 256, 0, stream>>>(s, We1, U, nullptr, 256, 128, 128, 1.f);
    bond_mfma<<<2 * N_MOLS, 512, 0, stream>>>(U, pos, e, We1, be1, We2, be2, out + 131072);

    pos_copy<<<96, 256, 0, stream>>>(pos, out + 131072 + 1269760);
}

// Round 4
// 900.274 us; speedup vs baseline: 4.1410x; 1.0682x over previous
//
#include <hip/hip_runtime.h>
#include <hip/hip_bf16.h>
#include <cstdint>
#include <cstddef>

#define N_MOLS 256
#define N_PER  32
#define NN     8192
#define EDGES  253952
#define SDIM_  256
#define EDIM_  32
#define NAF_   16
#define LAYERS_ 5

typedef __attribute__((ext_vector_type(8)))  short bf16x8;
typedef __attribute__((ext_vector_type(16))) float f32x16;

__device__ __forceinline__ float silu_f(float x) {
    return x / (1.f + __expf(-x));
}
__device__ __forceinline__ short bfc(float f) {
    __hip_bfloat16 h = __float2bfloat16(f);
    return __builtin_bit_cast(short, h);
}
__device__ __forceinline__ float bf2f(short h) {
    union { uint32_t u; float f; } v; v.u = ((uint32_t)(unsigned short)h) << 16; return v.f;
}
#define ONEBF ((short)0x3F80)

// ---------------------------------------------------------------------------
// node init: h = [x|z]@Wam+bam; s = h[:,:256]; pos = rot[mol]@h[:,256:259]
// ---------------------------------------------------------------------------
__global__ __launch_bounds__(256) void node_init(
    const float* __restrict__ x, const float* __restrict__ z,
    const float* __restrict__ rot, const float* __restrict__ Wam,
    const float* __restrict__ bam, float* __restrict__ s, float* __restrict__ pos)
{
    const int n = blockIdx.x, t = threadIdx.x;
    __shared__ float xz[80];
    __shared__ float praw[3];
    if (t < 16)      xz[t] = x[n * 16 + t];
    else if (t < 80) xz[t] = z[n * 64 + (t - 16)];
    __syncthreads();
    float acc = bam[t];
    #pragma unroll 8
    for (int k = 0; k < 80; ++k) acc += xz[k] * Wam[k * 259 + t];
    s[(size_t)n * SDIM_ + t] = acc;
    if (t < 3) {
        const int j2 = 256 + t;
        float a2 = bam[j2];
        for (int k = 0; k < 80; ++k) a2 += xz[k] * Wam[k * 259 + j2];
        praw[t] = a2;
    }
    __syncthreads();
    if (t < 3) {
        const int mol = n >> 5;
        float p = 0.f;
        for (int jj = 0; jj < 3; ++jj) p += rot[mol * 9 + t * 3 + jj] * praw[jj];
        pos[n * 3 + t] = p;
    }
}

// ---------------------------------------------------------------------------
// edge feature init (bf16 out), tgt-major: e[((mol*32+n)*31+rr)*32+c]
// ---------------------------------------------------------------------------
__global__ __launch_bounds__(256) void edge_init2(
    const float* __restrict__ ea, const float* __restrict__ Wbm,
    const float* __restrict__ bbm, short* __restrict__ ebuf)
{
    const int tile = blockIdx.x;          // mol*32 + n
    const int mol = tile >> 5, n = tile & 31;
    const int t = threadIdx.x;
    for (int i = t; i < 31 * 32; i += 256) {
        const int rr = i >> 5, c = i & 31;
        const int s_ = rr + (rr >= n ? 1 : 0);
        const int ge = (mol * 32 + s_) * 31 + (n - (n > s_ ? 1 : 0));
        float acc = bbm[c];
        #pragma unroll
        for (int k = 0; k < 5; ++k) acc += ea[(size_t)ge * 5 + k] * Wbm[k * 32 + c];
        ebuf[(size_t)tile * 31 * 32 + i] = bfc(acc);
    }
}

// ---------------------------------------------------------------------------
// bf16 MFMA GEMM: C[M,N] = act(alpha*(A@B) + bias) (+= if ACCUM)
// Optional POSTAIL: blocks (x==1, y<48) additionally do pos += pd/31.
// ---------------------------------------------------------------------------
template<int ACT, int ACCUM, int POSTAIL>
__global__ __launch_bounds__(256) void gemm_mfma(
    const float* __restrict__ A, const float* __restrict__ B,
    float* __restrict__ C, const float* __restrict__ bias,
    int K, int N, int ldb, float alpha,
    float* __restrict__ pos, const float* __restrict__ pd)
{
    const int n0 = blockIdx.x * 64, m0 = blockIdx.y * 128;
    const int t = threadIdx.x;
    const int wave = t >> 6, lane = t & 63;
    const int l = lane & 31, half = lane >> 5;
    const int wm = wave & 1, wn = wave >> 1;
    __shared__ __align__(16) short sA[128][40];
    __shared__ __align__(16) short sBt[64][40];
    f32x16 acc0 = {}, acc1 = {};
    const int mA = t >> 1, koA = (t & 1) * 16;
    const int krB = t >> 3, ncB = (t & 7) * 8;
    for (int k0 = 0; k0 < K; k0 += 32) {
        {
            const float* ap = A + (size_t)(m0 + mA) * K + k0 + koA;
            const float4 a0 = *(const float4*)(ap);
            const float4 a1 = *(const float4*)(ap + 4);
            const float4 a2 = *(const float4*)(ap + 8);
            const float4 a3 = *(const float4*)(ap + 12);
            bf16x8 p0, p1;
            p0[0]=bfc(a0.x); p0[1]=bfc(a0.y); p0[2]=bfc(a0.z); p0[3]=bfc(a0.w);
            p0[4]=bfc(a1.x); p0[5]=bfc(a1.y); p0[6]=bfc(a1.z); p0[7]=bfc(a1.w);
            p1[0]=bfc(a2.x); p1[1]=bfc(a2.y); p1[2]=bfc(a2.z); p1[3]=bfc(a2.w);
            p1[4]=bfc(a3.x); p1[5]=bfc(a3.y); p1[6]=bfc(a3.z); p1[7]=bfc(a3.w);
            *(bf16x8*)&sA[mA][koA]     = p0;
            *(bf16x8*)&sA[mA][koA + 8] = p1;
        }
        {
            const float* bp = B + (size_t)(k0 + krB) * ldb + n0 + ncB;
            const float4 b0 = *(const float4*)(bp);
            const float4 b1_ = *(const float4*)(bp + 4);
            sBt[ncB + 0][krB] = bfc(b0.x);  sBt[ncB + 1][krB] = bfc(b0.y);
            sBt[ncB + 2][krB] = bfc(b0.z);  sBt[ncB + 3][krB] = bfc(b0.w);
            sBt[ncB + 4][krB] = bfc(b1_.x); sBt[ncB + 5][krB] = bfc(b1_.y);
            sBt[ncB + 6][krB] = bfc(b1_.z); sBt[ncB + 7][krB] = bfc(b1_.w);
        }
        __syncthreads();
        #pragma unroll
        for (int ks = 0; ks < 2; ++ks) {
            const bf16x8 bfrag = *(const bf16x8*)&sBt[wn * 32 + l][ks * 16 + half * 8];
            const bf16x8 afr0  = *(const bf16x8*)&sA[wm * 64 + l][ks * 16 + half * 8];
            const bf16x8 afr1  = *(const bf16x8*)&sA[wm * 64 + 32 + l][ks * 16 + half * 8];
            acc0 = __builtin_amdgcn_mfma_f32_32x32x16_bf16(afr0, bfrag, acc0, 0,0,0);
            acc1 = __builtin_amdgcn_mfma_f32_32x32x16_bf16(afr1, bfrag, acc1, 0,0,0);
        }
        __syncthreads();
    }
    const int n = n0 + wn * 32 + l;
    const float bv = bias ? bias[n] : 0.f;
    #pragma unroll
    for (int r = 0; r < 16; ++r) {
        const int row = (r & 3) + 8 * (r >> 2) + 4 * half;
        {
            const int m = m0 + wm * 64 + row;
            float v = alpha * acc0[r] + bv;
            if (ACT) v = silu_f(v);
            if (ACCUM) C[(size_t)m * N + n] += v; else C[(size_t)m * N + n] = v;
        }
        {
            const int m = m0 + wm * 64 + 32 + row;
            float v = alpha * acc1[r] + bv;
            if (ACT) v = silu_f(v);
            if (ACCUM) C[(size_t)m * N + n] += v; else C[(size_t)m * N + n] = v;
        }
    }
    if (POSTAIL && blockIdx.x == 1 && blockIdx.y < 48) {
        const int i = (blockIdx.y * 256 + t) * 2;
        pos[i]     += pd[i]     * (1.f / 31.f);
        pos[i + 1] += pd[i + 1] * (1.f / 31.f);
    }
}

// ---------------------------------------------------------------------------
// Dual GEMM: one dispatch computes SA = s@W1a and SB = s@W1b.
// grid (8, 64): x<4 -> SA cols x*64; x>=4 -> SB cols (x-4)*64.
// ---------------------------------------------------------------------------
__global__ __launch_bounds__(256) void gemm_dual(
    const float* __restrict__ A, const float* __restrict__ B0,
    const float* __restrict__ B1, float* __restrict__ C0, float* __restrict__ C1)
{
    const int K = 256, N = 256, ldb = 256;
    const float* B = (blockIdx.x < 4) ? B0 : B1;
    float* C = (blockIdx.x < 4) ? C0 : C1;
    const int n0 = (blockIdx.x & 3) * 64, m0 = blockIdx.y * 128;
    const int t = threadIdx.x;
    const int wave = t >> 6, lane = t & 63;
    const int l = lane & 31, half = lane >> 5;
    const int wm = wave & 1, wn = wave >> 1;
    __shared__ __align__(16) short sA[128][40];
    __shared__ __align__(16) short sBt[64][40];
    f32x16 acc0 = {}, acc1 = {};
    const int mA = t >> 1, koA = (t & 1) * 16;
    const int krB = t >> 3, ncB = (t & 7) * 8;
    for (int k0 = 0; k0 < K; k0 += 32) {
        {
            const float* ap = A + (size_t)(m0 + mA) * K + k0 + koA;
            const float4 a0 = *(const float4*)(ap);
            const float4 a1 = *(const float4*)(ap + 4);
            const float4 a2 = *(const float4*)(ap + 8);
            const float4 a3 = *(const float4*)(ap + 12);
            bf16x8 p0, p1;
            p0[0]=bfc(a0.x); p0[1]=bfc(a0.y); p0[2]=bfc(a0.z); p0[3]=bfc(a0.w);
            p0[4]=bfc(a1.x); p0[5]=bfc(a1.y); p0[6]=bfc(a1.z); p0[7]=bfc(a1.w);
            p1[0]=bfc(a2.x); p1[1]=bfc(a2.y); p1[2]=bfc(a2.z); p1[3]=bfc(a2.w);
            p1[4]=bfc(a3.x); p1[5]=bfc(a3.y); p1[6]=bfc(a3.z); p1[7]=bfc(a3.w);
            *(bf16x8*)&sA[mA][koA]     = p0;
            *(bf16x8*)&sA[mA][koA + 8] = p1;
        }
        {
            const float* bp = B + (size_t)(k0 + krB) * ldb + n0 + ncB;
            const float4 b0 = *(const float4*)(bp);
            const float4 b1_ = *(const float4*)(bp + 4);
            sBt[ncB + 0][krB] = bfc(b0.x);  sBt[ncB + 1][krB] = bfc(b0.y);
            sBt[ncB + 2][krB] = bfc(b0.z);  sBt[ncB + 3][krB] = bfc(b0.w);
            sBt[ncB + 4][krB] = bfc(b1_.x); sBt[ncB + 5][krB] = bfc(b1_.y);
            sBt[ncB + 6][krB] = bfc(b1_.z); sBt[ncB + 7][krB] = bfc(b1_.w);
        }
        __syncthreads();
        #pragma unroll
        for (int ks = 0; ks < 2; ++ks) {
            const bf16x8 bfrag = *(const bf16x8*)&sBt[wn * 32 + l][ks * 16 + half * 8];
            const bf16x8 afr0  = *(const bf16x8*)&sA[wm * 64 + l][ks * 16 + half * 8];
            const bf16x8 afr1  = *(const bf16x8*)&sA[wm * 64 + 32 + l][ks * 16 + half * 8];
            acc0 = __builtin_amdgcn_mfma_f32_32x32x16_bf16(afr0, bfrag, acc0, 0,0,0);
            acc1 = __builtin_amdgcn_mfma_f32_32x32x16_bf16(afr1, bfrag, acc1, 0,0,0);
        }
        __syncthreads();
    }
    const int n = n0 + wn * 32 + l;
    #pragma unroll
    for (int r = 0; r < 16; ++r) {
        const int row = (r & 3) + 8 * (r >> 2) + 4 * half;
        C[(size_t)(m0 + wm * 64 + row) * N + n]      = acc0[r];
        C[(size_t)(m0 + wm * 64 + 32 + row) * N + n] = acc1[r];
    }
}

// ---------------------------------------------------------------------------
// MFMA edge kernel. Grid 512 (2 blocks/mol), 512 thr (8 waves).
// ebuf is bf16 now: A-fragments load directly; e-update RMW in bf16.
// ---------------------------------------------------------------------------
__global__ __launch_bounds__(512) void edge_mfma(
    const float* __restrict__ SA, const float* __restrict__ SB,
    const float* __restrict__ pos, short* __restrict__ ebuf,
    const float* __restrict__ W1, const float* __restrict__ b1,
    const float* __restrict__ W2, const float* __restrict__ b2,
    float* __restrict__ Hbuf, float* __restrict__ pdelta)
{
    const int blk = blockIdx.x;
    const int mol = blk >> 1;
    const int nbase = (blk & 1) * 16;
    const int t = threadIdx.x;
    const int wave = t >> 6, lane = t & 63;
    const int l = lane & 31, half = lane >> 5;
    const int node0 = mol * 32;

    __shared__ __align__(16) short sBg[256][72];    // 36 KB, 9 slots x 8
    __shared__ __align__(16) short sHdn[8][32][40]; // 20 KB (also W2e staging)
    __shared__ float sPosS[32][4];
    __shared__ float sRn[8][32][4];
    __shared__ short sW1da[2][256];

    {   // stage sBg
        const int j = t & 255;
        const int k0s = (t >> 8) * 32;
        for (int kk = 0; kk < 32; ++kk) {
            const int k = k0s + kk;
            const float v = (k < 32) ? W1[(size_t)(512 + k) * 256 + j]
                                     : SA[(size_t)(node0 + (k - 32)) * 256 + j];
            const int slot = ((k >> 3) + 3 * ((j >> 3) & 3)) & 7;
            sBg[j][slot * 8 + (k & 7)] = bfc(v);
        }
    }
    if (t < 256) {
        sW1da[0][t] = bfc(W1[(size_t)544 * 256 + t]);
        sW1da[1][t] = bfc(W1[(size_t)545 * 256 + t]);
    }
    if (t < 96) sPosS[t / 3][t % 3] = pos[node0 * 3 + t];

    // stage W2e cols 321..352 into sHdn-aliased scratch (coalesced), then frags
    short* sW2e = &sHdn[0][0][0];
    for (int i = 0; i < 16; ++i) {
        const int gi = i * 512 + t;
        const int c = gi & 31, j = gi >> 5;
        const int kk = j >> 4, hw = (j >> 3) & 1, jj = j & 7;
        sW2e[(size_t)(kk * 64 + hw * 32 + c) * 8 + jj] = bfc(W2[(size_t)j * 353 + 321 + c]);
    }
    __syncthreads();
    bf16x8 w2efr[16];
    #pragma unroll
    for (int kk = 0; kk < 16; ++kk)
        w2efr[kk] = *(const bf16x8*)&sW2e[(size_t)(kk * 64 + lane) * 8];
    float w2pv[8], b1v[8];
    short w1dv[8], w1av[8];
    #pragma unroll
    for (int cb = 0; cb < 8; ++cb) {
        w2pv[cb] = W2[(size_t)(cb * 32 + l) * 353 + 320];
        b1v[cb]  = b1[cb * 32 + l];
        w1dv[cb] = sW1da[0][cb * 32 + l];
        w1av[cb] = sW1da[1][cb * 32 + l];
    }
    const float b2e = b2[321 + l];
    const float b2p = b2[320];
    int bslot[4];
    #pragma unroll
    for (int ks = 0; ks < 4; ++ks)
        bslot[ks] = ((ks * 2 + half) + 3 * ((l >> 3) & 3)) & 7;
    __syncthreads();   // all waves done reading sW2e before sHdn reuse

    for (int ni = 0; ni < 2; ++ni) {
        const int n = nbase + wave + ni * 8;
        const int rrc = (l < 31) ? l : 30;
        const int src = rrc + (rrc >= n ? 1 : 0);
        const float ax = sPosS[n][0],  ay = sPosS[n][1],  az = sPosS[n][2];
        const float bx = sPosS[src][0], by = sPosS[src][1], bz = sPosS[src][2];
        const float rx = ax - bx, ry = ay - by, rz = az - bz;
        const float av = ax * bx + ay * by + az * bz;
        const float dd = sqrtf(fmaxf(rx * rx + ry * ry + rz * rz, 1e-6f));
        const float inv = 1.f / (1.f + dd);
        if (half == 0) {
            const bool pad = (l == 31);
            sRn[wave][l][0] = pad ? 0.f : rx * inv;
            sRn[wave][l][1] = pad ? 0.f : ry * inv;
            sRn[wave][l][2] = pad ? 0.f : rz * inv;
        }
        // A fragments: direct bf16 loads from ebuf
        const short* ebase = ebuf + ((size_t)((mol * 32 + n) * 31 + l)) * 32;
        const bf16x8 fr0 = *(const bf16x8*)(ebase + half * 8);
        const bf16x8 fr1 = *(const bf16x8*)(ebase + 16 + half * 8);
        bf16x8 fr2 = {}, fr3, fr4;
        if (half == 0) { fr2[0] = bfc(dd); fr2[1] = bfc(av); }
        #pragma unroll
        for (int jj = 0; jj < 8; ++jj) {
            fr3[jj] = (half * 8 + jj == src)      ? ONEBF : (short)0;
            fr4[jj] = (16 + half * 8 + jj == src) ? ONEBF : (short)0;
        }

        f32x16 accC = {};
        float pp[16];
        #pragma unroll
        for (int r = 0; r < 16; ++r) pp[r] = 0.f;
        float Hacc[8];

        const int g = l >> 3, jlow = l & 7;
        #pragma unroll
        for (int cb = 0; cb < 8; ++cb) {
            const float sbv = SB[(size_t)(node0 + n) * 256 + cb * 32 + l] + b1v[cb];
            f32x16 acc;
            #pragma unroll
            for (int r = 0; r < 16; ++r) acc[r] = sbv;
            {
                const short* brow = &sBg[cb * 32 + l][0];
                acc = __builtin_amdgcn_mfma_f32_32x32x16_bf16(fr0, *(const bf16x8*)(brow + bslot[0]*8), acc, 0,0,0);
                acc = __builtin_amdgcn_mfma_f32_32x32x16_bf16(fr1, *(const bf16x8*)(brow + bslot[1]*8), acc, 0,0,0);
                acc = __builtin_amdgcn_mfma_f32_32x32x16_bf16(fr3, *(const bf16x8*)(brow + bslot[2]*8), acc, 0,0,0);
                acc = __builtin_amdgcn_mfma_f32_32x32x16_bf16(fr4, *(const bf16x8*)(brow + bslot[3]*8), acc, 0,0,0);
                bf16x8 frB2 = {};
                if (half == 0) { frB2[0] = w1dv[cb]; frB2[1] = w1av[cb]; }
                acc = __builtin_amdgcn_mfma_f32_32x32x16_bf16(fr2, frB2, acc, 0,0,0);
            }
            float hs = 0.f;
            #pragma unroll
            for (int r = 0; r < 16; ++r) {
                const int e = (r & 3) + 8 * (r >> 2) + 4 * half;
                float h = silu_f(acc[r]);
                if (half == 1 && r == 15) h = 0.f;   // pad row 31
                hs += h;
                pp[r] += h * w2pv[cb];
                sHdn[wave][e][((g + (e >> 3)) & 3) * 8 + jlow] = bfc(h);
            }
            Hacc[cb] = hs;
            #pragma unroll
            for (int q = 0; q < 2; ++q) {
                const int g2 = q * 2 + half;
                const bf16x8 afr = *(const bf16x8*)&sHdn[wave][l][((g2 + (l >> 3)) & 3) * 8];
                accC = __builtin_amdgcn_mfma_f32_32x32x16_bf16(afr, w2efr[cb * 2 + q], accC, 0,0,0);
            }
        }
        // H
        #pragma unroll
        for (int cb = 0; cb < 8; ++cb) {
            const float v = Hacc[cb] + __shfl_xor(Hacc[cb], 32, 64);
            if (lane < 32) Hbuf[(size_t)(node0 + n) * 256 + cb * 32 + lane] = v;
        }
        // p butterfly over 32 j-lanes per half
        #pragma unroll
        for (int m = 1; m <= 16; m <<= 1) {
            #pragma unroll
            for (int r = 0; r < 16; ++r) pp[r] += __shfl_xor(pp[r], m, 64);
        }
        // pd = sum rn * p
        float pd0 = 0.f, pd1 = 0.f, pd2 = 0.f;
        #pragma unroll
        for (int r = 0; r < 16; ++r) {
            const int e = (r & 3) + 8 * (r >> 2) + 4 * half;
            const float pfull = (half == 1 && r == 15) ? 0.f : (pp[r] + b2p);
            pd0 += sRn[wave][e][0] * pfull;
            pd1 += sRn[wave][e][1] * pfull;
            pd2 += sRn[wave][e][2] * pfull;
        }
        pd0 += __shfl_xor(pd0, 32, 64);
        pd1 += __shfl_xor(pd1, 32, 64);
        pd2 += __shfl_xor(pd2, 32, 64);
        if (lane == 0) {
            pdelta[(size_t)(node0 + n) * 3 + 0] = pd0;
            pdelta[(size_t)(node0 + n) * 3 + 1] = pd1;
            pdelta[(size_t)(node0 + n) * 3 + 2] = pd2;
        }
        // e update (bf16 RMW)
        #pragma unroll
        for (int r = 0; r < 16; ++r) {
            const int e = (r & 3) + 8 * (r >> 2) + 4 * half;
            if (e < 31) {
                short* ep = ebuf + ((size_t)((mol * 32 + n) * 31 + e)) * 32 + l;
                *ep = bfc(bf2f(*ep) + accC[r] + b2e);
            }
        }
    }
}

// ---------------------------------------------------------------------------
// MFMA bond kernel (bf16 ebuf reads). Grid 512, 512 thr.
// ---------------------------------------------------------------------------
__global__ __launch_bounds__(512) void bond_mfma(
    const float* __restrict__ U, const float* __restrict__ pos,
    const short* __restrict__ ebuf, const float* __restrict__ We1,
    const float* __restrict__ be1, const float* __restrict__ We2,
    const float* __restrict__ be2, float* __restrict__ outB)
{
    const int blk = blockIdx.x;
    const int mol = blk >> 1;
    const int nbase = (blk & 1) * 16;
    const int t = threadIdx.x;
    const int wave = t >> 6, lane = t & 63;
    const int l = lane & 31, half = lane >> 5;
    const int node0 = mol * 32;

    __shared__ __align__(16) short sBg2[128][72];
    __shared__ __align__(16) short sHdnB[8][32][40];
    __shared__ float sPosS[32][4];
    __shared__ short sWd[128];

    {
        const int j = t & 127, kq = t >> 7;
        for (int kk = 0; kk < 16; ++kk) {
            const int k = kq * 16 + kk;
            const float v = (k < 32) ? We1[(size_t)(256 + k) * 128 + j]
                                     : U[(size_t)(node0 + (k - 32)) * 128 + j];
            const int slot = ((k >> 3) + 3 * ((j >> 3) & 3)) & 7;
            sBg2[j][slot * 8 + (k & 7)] = bfc(v);
        }
    }
    if (t < 128) sWd[t] = bfc(We1[(size_t)288 * 128 + t]);
    if (t < 96) sPosS[t / 3][t % 3] = pos[node0 * 3 + t];

    bf16x8 w2fr[8];
    #pragma unroll
    for (int kk = 0; kk < 8; ++kk) {
        #pragma unroll
        for (int jj = 0; jj < 8; ++jj) {
            const int k = kk * 16 + half * 8 + jj;
            w2fr[kk][jj] = (l < 5) ? bfc(We2[(size_t)k * 5 + l]) : (short)0;
        }
    }
    float be1v[4];
    #pragma unroll
    for (int cb = 0; cb < 4; ++cb) be1v[cb] = be1[cb * 32 + l];
    const float be2v = (l < 5) ? be2[l] : 0.f;
    int bslot[4];
    #pragma unroll
    for (int ks = 0; ks < 4; ++ks)
        bslot[ks] = ((ks * 2 + half) + 3 * ((l >> 3) & 3)) & 7;
    __syncthreads();

    for (int ni = 0; ni < 2; ++ni) {
        const int n = nbase + wave + ni * 8;
        const int rrc = (l < 31) ? l : 30;
        const int src = rrc + (rrc >= n ? 1 : 0);
        const float rx = sPosS[n][0] - sPosS[src][0];
        const float ry = sPosS[n][1] - sPosS[src][1];
        const float rz = sPosS[n][2] - sPosS[src][2];
        const float dd = sqrtf(fmaxf(rx * rx + ry * ry + rz * rz, 1e-6f));

        const short* ebase = ebuf + ((size_t)((mol * 32 + n) * 31 + l)) * 32;
        const bf16x8 fr0 = *(const bf16x8*)(ebase + half * 8);
        const bf16x8 fr1 = *(const bf16x8*)(ebase + 16 + half * 8);
        bf16x8 fr2 = {}, fr3, fr4;
        if (half == 0) fr2[0] = bfc(dd);
        #pragma unroll
        for (int jj = 0; jj < 8; ++jj) {
            fr3[jj] = (half * 8 + jj == src)      ? ONEBF : (short)0;
            fr4[jj] = (16 + half * 8 + jj == src) ? ONEBF : (short)0;
        }

        f32x16 accC = {};
        const int g = l >> 3, jlow = l & 7;
        #pragma unroll
        for (int cb = 0; cb < 4; ++cb) {
            const float uin = U[(size_t)(node0 + n) * 128 + cb * 32 + l] + be1v[cb];
            f32x16 acc;
            #pragma unroll
            for (int r = 0; r < 16; ++r) acc[r] = uin;
            {
                const short* brow = &sBg2[cb * 32 + l][0];
                acc = __builtin_amdgcn_mfma_f32_32x32x16_bf16(fr0, *(const bf16x8*)(brow + bslot[0]*8), acc, 0,0,0);
                acc = __builtin_amdgcn_mfma_f32_32x32x16_bf16(fr1, *(const bf16x8*)(brow + bslot[1]*8), acc, 0,0,0);
                acc = __builtin_amdgcn_mfma_f32_32x32x16_bf16(fr3, *(const bf16x8*)(brow + bslot[2]*8), acc, 0,0,0);
                acc = __builtin_amdgcn_mfma_f32_32x32x16_bf16(fr4, *(const bf16x8*)(brow + bslot[3]*8), acc, 0,0,0);
                bf16x8 frWd = {};
                if (half == 0) frWd[0] = sWd[cb * 32 + l];
                acc = __builtin_amdgcn_mfma_f32_32x32x16_bf16(fr2, frWd, acc, 0,0,0);
            }
            #pragma unroll
            for (int r = 0; r < 16; ++r) {
                const int e = (r & 3) + 8 * (r >> 2) + 4 * half;
                sHdnB[wave][e][((g + (e >> 3)) & 3) * 8 + jlow] = bfc(silu_f(acc[r]));
            }
            #pragma unroll
            for (int q = 0; q < 2; ++q) {
                const int g2 = q * 2 + half;
                const bf16x8 afr = *(const bf16x8*)&sHdnB[wave][l][((g2 + (l >> 3)) & 3) * 8];
                accC = __builtin_amdgcn_mfma_f32_32x32x16_bf16(afr, w2fr[cb * 2 + q], accC, 0,0,0);
            }
        }
        if (l < 5) {
            #pragma unroll
            for (int r = 0; r < 16; ++r) {
                const int e = (r & 3) + 8 * (r >> 2) + 4 * half;
                if (e < 31) {
                    const int s_ = e + (e >= n ? 1 : 0);
                    const int ge = (mol * 32 + s_) * 31 + (n - (n > s_ ? 1 : 0));
                    outB[(size_t)ge * 5 + l] = accC[r] + be2v;
                }
            }
        }
    }
}

// ---------------------------------------------------------------------------
__global__ __launch_bounds__(256) void pos_copy(const float* __restrict__ pos,
                                                float* __restrict__ out)
{
    const int i = blockIdx.x * 256 + threadIdx.x;
    out[i] = pos[i];
}

// ---------------------------------------------------------------------------
__global__ __launch_bounds__(256) void atoms_kernel(
    const float* __restrict__ tmp, const float* __restrict__ Wh2,
    const float* __restrict__ bh2, float* __restrict__ outA)
{
    const int gid = blockIdx.x * 256 + threadIdx.x;
    const int n = gid >> 4, o = gid & 15;
    float acc = bh2[o];
    #pragma unroll 8
    for (int k = 0; k < SDIM_; ++k) acc += tmp[(size_t)n * SDIM_ + k] * Wh2[k * NAF_ + o];
    outA[gid] = acc;
}

// ---------------------------------------------------------------------------
extern "C" void kernel_launch(void* const* d_in, const int* in_sizes, int n_in,
                              void* d_out, int out_size, void* d_ws, size_t ws_size,
                              hipStream_t stream) {
    const float* x   = (const float*)d_in[0];
    const float* z   = (const float*)d_in[1];
    const float* rot = (const float*)d_in[2];
    const float* ea  = (const float*)d_in[4];
    const float* Wam = (const float*)d_in[6];
    const float* bam = (const float*)d_in[7];
    const float* Wbm = (const float*)d_in[8];
    const float* bbm = (const float*)d_in[9];
    const float* gW1 = (const float*)d_in[10];
    const float* gb1 = (const float*)d_in[11];
    const float* gW2 = (const float*)d_in[12];
    const float* gb2 = (const float*)d_in[13];
    const float* Wh1 = (const float*)d_in[14];
    const float* bh1 = (const float*)d_in[15];
    const float* Wh2 = (const float*)d_in[16];
    const float* bh2 = (const float*)d_in[17];
    const float* We1 = (const float*)d_in[18];
    const float* be1 = (const float*)d_in[19];
    const float* We2 = (const float*)d_in[20];
    const float* be2 = (const float*)d_in[21];
    float* out = (float*)d_out;

    float* ws  = (float*)d_ws;
    float* s   = ws;                    // 8192*256
    float* pos = ws + 2097152;          // 8192*3
    short* e   = (short*)(ws + 2121728);// 8192*31*32 bf16 (within old float region)
    float* SA  = ws + 10248192;         // 8192*256
    float* SB  = ws + 12345344;         // 8192*256
    float* H   = ws + 14442496;         // 8192*256
    float* pd  = ws + 16539648;         // 8192*3
    float* tmp = SA;
    float* U   = H;

    node_init<<<NN, 256, 0, stream>>>(x, z, rot, Wam, bam, s, pos);
    edge_init2<<<NN, 256, 0, stream>>>(ea, Wbm, bbm, e);

    for (int l = 0; l < LAYERS_; ++l) {
        const float* W1 = gW1 + (size_t)l * 546 * 256;
        const float* b1 = gb1 + l * 256;
        const float* W2 = gW2 + (size_t)l * 256 * 353;
        const float* b2 = gb2 + l * 353;
        gemm_dual<<<dim3(8, 64), 256, 0, stream>>>(s, W1, W1 + 256 * 256, SA, SB);
        edge_mfma<<<2 * N_MOLS, 512, 0, stream>>>(SA, SB, pos, e, W1, b1, W2, b2, H, pd);
        // s += (H @ W2[:,0:256])/31 + b2[0:256]; fused: pos += pd/31
        gemm_mfma<0,1,1><<<dim3(4, 64), 256, 0, stream>>>(H, W2, s, b2, 256, 256, 353, 1.f / 31.f, pos, pd);
    }

    gemm_mfma<1,0,0><<<dim3(4, 64), 256, 0, stream>>>(s, Wh1, tmp, bh1, 256, 256, 256, 1.f, nullptr, nullptr);
    atoms_kernel<<<512, 256, 0, stream>>>(tmp, Wh2, bh2, out);

    gemm_mfma<0,0,0><<<dim3(2, 64), 256, 0, stream>>>(s, We1, U, nullptr, 256, 128, 128, 1.f, nullptr, nullptr);
    bond_mfma<<<2 * N_MOLS, 512, 0, stream>>>(U, pos, e, We1, be1, We2, be2, out + 131072);

    pos_copy<<<96, 256, 0, stream>>>(pos, out + 131072 + 1269760);
}

// Round 5
// 877.500 us; speedup vs baseline: 4.2484x; 1.0260x over previous
//
#include <hip/hip_runtime.h>
#include <hip/hip_bf16.h>
#include <cstdint>
#include <cstddef>

#define N_MOLS 256
#define N_PER  32
#define NN     8192
#define EDGES  253952
#define SDIM_  256
#define EDIM_  32
#define NAF_   16
#define LAYERS_ 5

typedef __attribute__((ext_vector_type(8)))  short bf16x8;
typedef __attribute__((ext_vector_type(16))) float f32x16;

__device__ __forceinline__ float silu_f(float x) {
    return x / (1.f + __expf(-x));
}
__device__ __forceinline__ short bfc(float f) {
    __hip_bfloat16 h = __float2bfloat16(f);
    return __builtin_bit_cast(short, h);
}
__device__ __forceinline__ float bf2f(short h) {
    union { uint32_t u; float f; } v; v.u = ((uint32_t)(unsigned short)h) << 16; return v.f;
}
#define ONEBF ((short)0x3F80)

// ---------------------------------------------------------------------------
// node init: h = [x|z]@Wam+bam; s = h[:,:256]; pos = rot[mol]@h[:,256:259]
// ---------------------------------------------------------------------------
__global__ __launch_bounds__(256) void node_init(
    const float* __restrict__ x, const float* __restrict__ z,
    const float* __restrict__ rot, const float* __restrict__ Wam,
    const float* __restrict__ bam, float* __restrict__ s, float* __restrict__ pos)
{
    const int n = blockIdx.x, t = threadIdx.x;
    __shared__ float xz[80];
    __shared__ float praw[3];
    if (t < 16)      xz[t] = x[n * 16 + t];
    else if (t < 80) xz[t] = z[n * 64 + (t - 16)];
    __syncthreads();
    float acc = bam[t];
    #pragma unroll 8
    for (int k = 0; k < 80; ++k) acc += xz[k] * Wam[k * 259 + t];
    s[(size_t)n * SDIM_ + t] = acc;
    if (t < 3) {
        const int j2 = 256 + t;
        float a2 = bam[j2];
        for (int k = 0; k < 80; ++k) a2 += xz[k] * Wam[k * 259 + j2];
        praw[t] = a2;
    }
    __syncthreads();
    if (t < 3) {
        const int mol = n >> 5;
        float p = 0.f;
        for (int jj = 0; jj < 3; ++jj) p += rot[mol * 9 + t * 3 + jj] * praw[jj];
        pos[n * 3 + t] = p;
    }
}

// ---------------------------------------------------------------------------
// edge feature init (bf16 out), tgt-major: e[((mol*32+n)*31+rr)*32+c]
// ---------------------------------------------------------------------------
__global__ __launch_bounds__(256) void edge_init2(
    const float* __restrict__ ea, const float* __restrict__ Wbm,
    const float* __restrict__ bbm, short* __restrict__ ebuf)
{
    const int tile = blockIdx.x;          // mol*32 + n
    const int mol = tile >> 5, n = tile & 31;
    const int t = threadIdx.x;
    for (int i = t; i < 31 * 32; i += 256) {
        const int rr = i >> 5, c = i & 31;
        const int s_ = rr + (rr >= n ? 1 : 0);
        const int ge = (mol * 32 + s_) * 31 + (n - (n > s_ ? 1 : 0));
        float acc = bbm[c];
        #pragma unroll
        for (int k = 0; k < 5; ++k) acc += ea[(size_t)ge * 5 + k] * Wbm[k * 32 + c];
        ebuf[(size_t)tile * 31 * 32 + i] = bfc(acc);
    }
}

// ---------------------------------------------------------------------------
// bf16 MFMA GEMM: C = act(alpha*(A@B) + bias) (+= if ACCUM).
// ABF: A is bf16 (pure-copy staging). OUTBF: C written as bf16.
// POSTAIL: blocks (x==1, y<48) additionally do pos += pd/31.
// ---------------------------------------------------------------------------
template<int ACT, int ACCUM, int POSTAIL, int ABF, int OUTBF>
__global__ __launch_bounds__(256) void gemm_mfma(
    const void* __restrict__ Av, const float* __restrict__ B,
    void* __restrict__ Cv, const float* __restrict__ bias,
    int K, int N, int ldb, float alpha,
    float* __restrict__ pos, const float* __restrict__ pd)
{
    const int n0 = blockIdx.x * 64, m0 = blockIdx.y * 128;
    const int t = threadIdx.x;
    const int wave = t >> 6, lane = t & 63;
    const int l = lane & 31, half = lane >> 5;
    const int wm = wave & 1, wn = wave >> 1;
    __shared__ __align__(16) short sA[128][40];
    __shared__ __align__(16) short sBt[64][40];
    f32x16 acc0 = {}, acc1 = {};
    const int mA = t >> 1, koA = (t & 1) * 16;
    const int krB = t >> 3, ncB = (t & 7) * 8;
    for (int k0 = 0; k0 < K; k0 += 32) {
        if (ABF) {
            const short* ap = (const short*)Av + (size_t)(m0 + mA) * K + k0 + koA;
            *(bf16x8*)&sA[mA][koA]     = *(const bf16x8*)(ap);
            *(bf16x8*)&sA[mA][koA + 8] = *(const bf16x8*)(ap + 8);
        } else {
            const float* ap = (const float*)Av + (size_t)(m0 + mA) * K + k0 + koA;
            const float4 a0 = *(const float4*)(ap);
            const float4 a1 = *(const float4*)(ap + 4);
            const float4 a2 = *(const float4*)(ap + 8);
            const float4 a3 = *(const float4*)(ap + 12);
            bf16x8 p0, p1;
            p0[0]=bfc(a0.x); p0[1]=bfc(a0.y); p0[2]=bfc(a0.z); p0[3]=bfc(a0.w);
            p0[4]=bfc(a1.x); p0[5]=bfc(a1.y); p0[6]=bfc(a1.z); p0[7]=bfc(a1.w);
            p1[0]=bfc(a2.x); p1[1]=bfc(a2.y); p1[2]=bfc(a2.z); p1[3]=bfc(a2.w);
            p1[4]=bfc(a3.x); p1[5]=bfc(a3.y); p1[6]=bfc(a3.z); p1[7]=bfc(a3.w);
            *(bf16x8*)&sA[mA][koA]     = p0;
            *(bf16x8*)&sA[mA][koA + 8] = p1;
        }
        {
            const float* bp = B + (size_t)(k0 + krB) * ldb + n0 + ncB;
            const float4 b0 = *(const float4*)(bp);
            const float4 b1_ = *(const float4*)(bp + 4);
            sBt[ncB + 0][krB] = bfc(b0.x);  sBt[ncB + 1][krB] = bfc(b0.y);
            sBt[ncB + 2][krB] = bfc(b0.z);  sBt[ncB + 3][krB] = bfc(b0.w);
            sBt[ncB + 4][krB] = bfc(b1_.x); sBt[ncB + 5][krB] = bfc(b1_.y);
            sBt[ncB + 6][krB] = bfc(b1_.z); sBt[ncB + 7][krB] = bfc(b1_.w);
        }
        __syncthreads();
        #pragma unroll
        for (int ks = 0; ks < 2; ++ks) {
            const bf16x8 bfrag = *(const bf16x8*)&sBt[wn * 32 + l][ks * 16 + half * 8];
            const bf16x8 afr0  = *(const bf16x8*)&sA[wm * 64 + l][ks * 16 + half * 8];
            const bf16x8 afr1  = *(const bf16x8*)&sA[wm * 64 + 32 + l][ks * 16 + half * 8];
            acc0 = __builtin_amdgcn_mfma_f32_32x32x16_bf16(afr0, bfrag, acc0, 0,0,0);
            acc1 = __builtin_amdgcn_mfma_f32_32x32x16_bf16(afr1, bfrag, acc1, 0,0,0);
        }
        __syncthreads();
    }
    const int n = n0 + wn * 32 + l;
    const float bv = bias ? bias[n] : 0.f;
    #pragma unroll
    for (int r = 0; r < 16; ++r) {
        const int row = (r & 3) + 8 * (r >> 2) + 4 * half;
        {
            const int m = m0 + wm * 64 + row;
            float v = alpha * acc0[r] + bv;
            if (ACT) v = silu_f(v);
            if (OUTBF) ((short*)Cv)[(size_t)m * N + n] = bfc(v);
            else if (ACCUM) ((float*)Cv)[(size_t)m * N + n] += v;
            else            ((float*)Cv)[(size_t)m * N + n] = v;
        }
        {
            const int m = m0 + wm * 64 + 32 + row;
            float v = alpha * acc1[r] + bv;
            if (ACT) v = silu_f(v);
            if (OUTBF) ((short*)Cv)[(size_t)m * N + n] = bfc(v);
            else if (ACCUM) ((float*)Cv)[(size_t)m * N + n] += v;
            else            ((float*)Cv)[(size_t)m * N + n] = v;
        }
    }
    if (POSTAIL && blockIdx.x == 1 && blockIdx.y < 48) {
        const int i = (blockIdx.y * 256 + t) * 2;
        pos[i]     += pd[i]     * (1.f / 31.f);
        pos[i + 1] += pd[i + 1] * (1.f / 31.f);
    }
}

// ---------------------------------------------------------------------------
// Dual GEMM (bf16 out): SA = s@W1a, SB = s@W1b in one dispatch.
// ---------------------------------------------------------------------------
__global__ __launch_bounds__(256) void gemm_dual(
    const float* __restrict__ A, const float* __restrict__ B0,
    const float* __restrict__ B1, short* __restrict__ C0, short* __restrict__ C1)
{
    const int K = 256, N = 256, ldb = 256;
    const float* B = (blockIdx.x < 4) ? B0 : B1;
    short* C = (blockIdx.x < 4) ? C0 : C1;
    const int n0 = (blockIdx.x & 3) * 64, m0 = blockIdx.y * 128;
    const int t = threadIdx.x;
    const int wave = t >> 6, lane = t & 63;
    const int l = lane & 31, half = lane >> 5;
    const int wm = wave & 1, wn = wave >> 1;
    __shared__ __align__(16) short sA[128][40];
    __shared__ __align__(16) short sBt[64][40];
    f32x16 acc0 = {}, acc1 = {};
    const int mA = t >> 1, koA = (t & 1) * 16;
    const int krB = t >> 3, ncB = (t & 7) * 8;
    for (int k0 = 0; k0 < K; k0 += 32) {
        {
            const float* ap = A + (size_t)(m0 + mA) * K + k0 + koA;
            const float4 a0 = *(const float4*)(ap);
            const float4 a1 = *(const float4*)(ap + 4);
            const float4 a2 = *(const float4*)(ap + 8);
            const float4 a3 = *(const float4*)(ap + 12);
            bf16x8 p0, p1;
            p0[0]=bfc(a0.x); p0[1]=bfc(a0.y); p0[2]=bfc(a0.z); p0[3]=bfc(a0.w);
            p0[4]=bfc(a1.x); p0[5]=bfc(a1.y); p0[6]=bfc(a1.z); p0[7]=bfc(a1.w);
            p1[0]=bfc(a2.x); p1[1]=bfc(a2.y); p1[2]=bfc(a2.z); p1[3]=bfc(a2.w);
            p1[4]=bfc(a3.x); p1[5]=bfc(a3.y); p1[6]=bfc(a3.z); p1[7]=bfc(a3.w);
            *(bf16x8*)&sA[mA][koA]     = p0;
            *(bf16x8*)&sA[mA][koA + 8] = p1;
        }
        {
            const float* bp = B + (size_t)(k0 + krB) * ldb + n0 + ncB;
            const float4 b0 = *(const float4*)(bp);
            const float4 b1_ = *(const float4*)(bp + 4);
            sBt[ncB + 0][krB] = bfc(b0.x);  sBt[ncB + 1][krB] = bfc(b0.y);
            sBt[ncB + 2][krB] = bfc(b0.z);  sBt[ncB + 3][krB] = bfc(b0.w);
            sBt[ncB + 4][krB] = bfc(b1_.x); sBt[ncB + 5][krB] = bfc(b1_.y);
            sBt[ncB + 6][krB] = bfc(b1_.z); sBt[ncB + 7][krB] = bfc(b1_.w);
        }
        __syncthreads();
        #pragma unroll
        for (int ks = 0; ks < 2; ++ks) {
            const bf16x8 bfrag = *(const bf16x8*)&sBt[wn * 32 + l][ks * 16 + half * 8];
            const bf16x8 afr0  = *(const bf16x8*)&sA[wm * 64 + l][ks * 16 + half * 8];
            const bf16x8 afr1  = *(const bf16x8*)&sA[wm * 64 + 32 + l][ks * 16 + half * 8];
            acc0 = __builtin_amdgcn_mfma_f32_32x32x16_bf16(afr0, bfrag, acc0, 0,0,0);
            acc1 = __builtin_amdgcn_mfma_f32_32x32x16_bf16(afr1, bfrag, acc1, 0,0,0);
        }
        __syncthreads();
    }
    const int n = n0 + wn * 32 + l;
    #pragma unroll
    for (int r = 0; r < 16; ++r) {
        const int row = (r & 3) + 8 * (r >> 2) + 4 * half;
        C[(size_t)(m0 + wm * 64 + row) * N + n]      = bfc(acc0[r]);
        C[(size_t)(m0 + wm * 64 + 32 + row) * N + n] = bfc(acc1[r]);
    }
}

// ---------------------------------------------------------------------------
// MFMA edge kernel. Grid 512 (2 blocks/mol), 512 thr (8 waves).
// p computed via broadcast-B MFMA (accP); pd via tiny LDS p-broadcast.
// SA/SB bf16 in, H bf16 out, ebuf bf16 RMW.
// ---------------------------------------------------------------------------
__global__ __launch_bounds__(512) void edge_mfma(
    const short* __restrict__ SA, const short* __restrict__ SB,
    const float* __restrict__ pos, short* __restrict__ ebuf,
    const float* __restrict__ W1, const float* __restrict__ b1,
    const float* __restrict__ W2, const float* __restrict__ b2,
    short* __restrict__ Hbuf, float* __restrict__ pdelta)
{
    const int blk = blockIdx.x;
    const int mol = blk >> 1;
    const int nbase = (blk & 1) * 16;
    const int t = threadIdx.x;
    const int wave = t >> 6, lane = t & 63;
    const int l = lane & 31, half = lane >> 5;
    const int node0 = mol * 32;

    __shared__ __align__(16) short sBg[256][72];    // 36 KB
    __shared__ __align__(16) short sHdn[8][32][40]; // 20 KB (aliased W2e staging)
    __shared__ float sPosS[32][4];
    __shared__ short sW1da[2][256];
    __shared__ short sW2p[256];
    __shared__ float sP[8][32];

    {   // stage sBg: k0..31 = W1c (fp32->bf16), k32..63 = SA rows (bf16 copy)
        const int j = t & 255;
        const int k0s = (t >> 8) * 32;
        for (int kk = 0; kk < 32; ++kk) {
            const int k = k0s + kk;
            const short v = (k < 32) ? bfc(W1[(size_t)(512 + k) * 256 + j])
                                     : SA[(size_t)(node0 + (k - 32)) * 256 + j];
            const int slot = ((k >> 3) + 3 * ((j >> 3) & 3)) & 7;
            sBg[j][slot * 8 + (k & 7)] = v;
        }
    }
    if (t < 256) {
        sW1da[0][t] = bfc(W1[(size_t)544 * 256 + t]);
        sW1da[1][t] = bfc(W1[(size_t)545 * 256 + t]);
        sW2p[t]     = bfc(W2[(size_t)t * 353 + 320]);
    }
    if (t < 96) sPosS[t / 3][t % 3] = pos[node0 * 3 + t];

    // stage W2e cols 321..352 into sHdn-aliased scratch, then to registers
    short* sW2e = &sHdn[0][0][0];
    for (int i = 0; i < 16; ++i) {
        const int gi = i * 512 + t;
        const int c = gi & 31, j = gi >> 5;
        const int kk = j >> 4, hw = (j >> 3) & 1, jj = j & 7;
        sW2e[(size_t)(kk * 64 + hw * 32 + c) * 8 + jj] = bfc(W2[(size_t)j * 353 + 321 + c]);
    }
    __syncthreads();
    bf16x8 w2efr[16];
    #pragma unroll
    for (int kk = 0; kk < 16; ++kk)
        w2efr[kk] = *(const bf16x8*)&sW2e[(size_t)(kk * 64 + lane) * 8];
    float b1v[8];
    short w1dv[8], w1av[8];
    #pragma unroll
    for (int cb = 0; cb < 8; ++cb) {
        b1v[cb]  = b1[cb * 32 + l];
        w1dv[cb] = sW1da[0][cb * 32 + l];
        w1av[cb] = sW1da[1][cb * 32 + l];
    }
    const float b2e = b2[321 + l];
    const float b2p = b2[320];
    int bslot[4];
    #pragma unroll
    for (int ks = 0; ks < 4; ++ks)
        bslot[ks] = ((ks * 2 + half) + 3 * ((l >> 3) & 3)) & 7;
    __syncthreads();   // all waves done reading sW2e before sHdn reuse

    for (int ni = 0; ni < 2; ++ni) {
        const int n = nbase + wave + ni * 8;
        const int rrc = (l < 31) ? l : 30;
        const int src = rrc + (rrc >= n ? 1 : 0);
        const float ax = sPosS[n][0],  ay = sPosS[n][1],  az = sPosS[n][2];
        const float bx = sPosS[src][0], by = sPosS[src][1], bz = sPosS[src][2];
        const float rx = ax - bx, ry = ay - by, rz = az - bz;
        const float av = ax * bx + ay * by + az * bz;
        const float dd = sqrtf(fmaxf(rx * rx + ry * ry + rz * rz, 1e-6f));
        const float inv = 1.f / (1.f + dd);
        const float rnx = rx * inv, rny = ry * inv, rnz = rz * inv;

        // A fragments: direct bf16 loads from ebuf
        const short* ebase = ebuf + ((size_t)((mol * 32 + n) * 31 + l)) * 32;
        const bf16x8 fr0 = *(const bf16x8*)(ebase + half * 8);
        const bf16x8 fr1 = *(const bf16x8*)(ebase + 16 + half * 8);
        bf16x8 fr2 = {}, fr3, fr4;
        if (half == 0) { fr2[0] = bfc(dd); fr2[1] = bfc(av); }
        #pragma unroll
        for (int jj = 0; jj < 8; ++jj) {
            fr3[jj] = (half * 8 + jj == src)      ? ONEBF : (short)0;
            fr4[jj] = (16 + half * 8 + jj == src) ? ONEBF : (short)0;
        }

        f32x16 accC = {}, accP = {};
        float Hacc[8];

        const int g = l >> 3, jlow = l & 7;
        #pragma unroll
        for (int cb = 0; cb < 8; ++cb) {
            const float sbv = bf2f(SB[(size_t)(node0 + n) * 256 + cb * 32 + l]) + b1v[cb];
            f32x16 acc;
            #pragma unroll
            for (int r = 0; r < 16; ++r) acc[r] = sbv;
            {
                const short* brow = &sBg[cb * 32 + l][0];
                acc = __builtin_amdgcn_mfma_f32_32x32x16_bf16(fr0, *(const bf16x8*)(brow + bslot[0]*8), acc, 0,0,0);
                acc = __builtin_amdgcn_mfma_f32_32x32x16_bf16(fr1, *(const bf16x8*)(brow + bslot[1]*8), acc, 0,0,0);
                acc = __builtin_amdgcn_mfma_f32_32x32x16_bf16(fr3, *(const bf16x8*)(brow + bslot[2]*8), acc, 0,0,0);
                acc = __builtin_amdgcn_mfma_f32_32x32x16_bf16(fr4, *(const bf16x8*)(brow + bslot[3]*8), acc, 0,0,0);
                bf16x8 frB2 = {};
                if (half == 0) { frB2[0] = w1dv[cb]; frB2[1] = w1av[cb]; }
                acc = __builtin_amdgcn_mfma_f32_32x32x16_bf16(fr2, frB2, acc, 0,0,0);
            }
            float hs = 0.f;
            #pragma unroll
            for (int r = 0; r < 16; ++r) {
                const int e = (r & 3) + 8 * (r >> 2) + 4 * half;
                float h = silu_f(acc[r]);
                if (half == 1 && r == 15) h = 0.f;   // pad row 31
                hs += h;
                sHdn[wave][e][((g + (e >> 3)) & 3) * 8 + jlow] = bfc(h);
            }
            Hacc[cb] = hs;
            #pragma unroll
            for (int q = 0; q < 2; ++q) {
                const int g2 = q * 2 + half;
                const bf16x8 afr  = *(const bf16x8*)&sHdn[wave][l][((g2 + (l >> 3)) & 3) * 8];
                const bf16x8 wpfr = *(const bf16x8*)&sW2p[cb * 32 + q * 16 + half * 8];
                accC = __builtin_amdgcn_mfma_f32_32x32x16_bf16(afr, w2efr[cb * 2 + q], accC, 0,0,0);
                accP = __builtin_amdgcn_mfma_f32_32x32x16_bf16(afr, wpfr, accP, 0,0,0);
            }
        }
        // H (bf16 out)
        #pragma unroll
        for (int cb = 0; cb < 8; ++cb) {
            const float v = Hacc[cb] + __shfl_xor(Hacc[cb], 32, 64);
            if (lane < 32) Hbuf[(size_t)(node0 + n) * 256 + cb * 32 + lane] = bfc(v);
        }
        // p: accP cols all equal; lanes l==0 (both halves) scatter 16 rows each
        if (l == 0) {
            #pragma unroll
            for (int q4 = 0; q4 < 4; ++q4) {
                float4 pv = { accP[q4 * 4 + 0], accP[q4 * 4 + 1],
                              accP[q4 * 4 + 2], accP[q4 * 4 + 3] };
                *(float4*)&sP[wave][q4 * 8 + 4 * half] = pv;
            }
        }
        // pd = sum_e rn[e] * (p[e] + b2p); lane l owns e=l (half0 only)
        const float pown = sP[wave][l];
        const float pfull = (half == 0 && l < 31) ? (pown + b2p) : 0.f;
        float pd0 = rnx * pfull, pd1 = rny * pfull, pd2 = rnz * pfull;
        #pragma unroll
        for (int m = 1; m <= 32; m <<= 1) {
            pd0 += __shfl_xor(pd0, m, 64);
            pd1 += __shfl_xor(pd1, m, 64);
            pd2 += __shfl_xor(pd2, m, 64);
        }
        if (lane == 0) {
            pdelta[(size_t)(node0 + n) * 3 + 0] = pd0;
            pdelta[(size_t)(node0 + n) * 3 + 1] = pd1;
            pdelta[(size_t)(node0 + n) * 3 + 2] = pd2;
        }
        // e update (bf16 RMW)
        #pragma unroll
        for (int r = 0; r < 16; ++r) {
            const int e = (r & 3) + 8 * (r >> 2) + 4 * half;
            if (e < 31) {
                short* ep = ebuf + ((size_t)((mol * 32 + n) * 31 + e)) * 32 + l;
                *ep = bfc(bf2f(*ep) + accC[r] + b2e);
            }
        }
    }
}

// ---------------------------------------------------------------------------
// MFMA bond kernel (bf16 ebuf + bf16 U). Grid 512, 512 thr.
// ---------------------------------------------------------------------------
__global__ __launch_bounds__(512) void bond_mfma(
    const short* __restrict__ U, const float* __restrict__ pos,
    const short* __restrict__ ebuf, const float* __restrict__ We1,
    const float* __restrict__ be1, const float* __restrict__ We2,
    const float* __restrict__ be2, float* __restrict__ outB)
{
    const int blk = blockIdx.x;
    const int mol = blk >> 1;
    const int nbase = (blk & 1) * 16;
    const int t = threadIdx.x;
    const int wave = t >> 6, lane = t & 63;
    const int l = lane & 31, half = lane >> 5;
    const int node0 = mol * 32;

    __shared__ __align__(16) short sBg2[128][72];
    __shared__ __align__(16) short sHdnB[8][32][40];
    __shared__ float sPosS[32][4];
    __shared__ short sWd[128];

    {
        const int j = t & 127, kq = t >> 7;
        for (int kk = 0; kk < 16; ++kk) {
            const int k = kq * 16 + kk;
            const short v = (k < 32) ? bfc(We1[(size_t)(256 + k) * 128 + j])
                                     : U[(size_t)(node0 + (k - 32)) * 128 + j];
            const int slot = ((k >> 3) + 3 * ((j >> 3) & 3)) & 7;
            sBg2[j][slot * 8 + (k & 7)] = v;
        }
    }
    if (t < 128) sWd[t] = bfc(We1[(size_t)288 * 128 + t]);
    if (t < 96) sPosS[t / 3][t % 3] = pos[node0 * 3 + t];

    bf16x8 w2fr[8];
    #pragma unroll
    for (int kk = 0; kk < 8; ++kk) {
        #pragma unroll
        for (int jj = 0; jj < 8; ++jj) {
            const int k = kk * 16 + half * 8 + jj;
            w2fr[kk][jj] = (l < 5) ? bfc(We2[(size_t)k * 5 + l]) : (short)0;
        }
    }
    float be1v[4];
    #pragma unroll
    for (int cb = 0; cb < 4; ++cb) be1v[cb] = be1[cb * 32 + l];
    const float be2v = (l < 5) ? be2[l] : 0.f;
    int bslot[4];
    #pragma unroll
    for (int ks = 0; ks < 4; ++ks)
        bslot[ks] = ((ks * 2 + half) + 3 * ((l >> 3) & 3)) & 7;
    __syncthreads();

    for (int ni = 0; ni < 2; ++ni) {
        const int n = nbase + wave + ni * 8;
        const int rrc = (l < 31) ? l : 30;
        const int src = rrc + (rrc >= n ? 1 : 0);
        const float rx = sPosS[n][0] - sPosS[src][0];
        const float ry = sPosS[n][1] - sPosS[src][1];
        const float rz = sPosS[n][2] - sPosS[src][2];
        const float dd = sqrtf(fmaxf(rx * rx + ry * ry + rz * rz, 1e-6f));

        const short* ebase = ebuf + ((size_t)((mol * 32 + n) * 31 + l)) * 32;
        const bf16x8 fr0 = *(const bf16x8*)(ebase + half * 8);
        const bf16x8 fr1 = *(const bf16x8*)(ebase + 16 + half * 8);
        bf16x8 fr2 = {}, fr3, fr4;
        if (half == 0) fr2[0] = bfc(dd);
        #pragma unroll
        for (int jj = 0; jj < 8; ++jj) {
            fr3[jj] = (half * 8 + jj == src)      ? ONEBF : (short)0;
            fr4[jj] = (16 + half * 8 + jj == src) ? ONEBF : (short)0;
        }

        f32x16 accC = {};
        const int g = l >> 3, jlow = l & 7;
        #pragma unroll
        for (int cb = 0; cb < 4; ++cb) {
            const float uin = bf2f(U[(size_t)(node0 + n) * 128 + cb * 32 + l]) + be1v[cb];
            f32x16 acc;
            #pragma unroll
            for (int r = 0; r < 16; ++r) acc[r] = uin;
            {
                const short* brow = &sBg2[cb * 32 + l][0];
                acc = __builtin_amdgcn_mfma_f32_32x32x16_bf16(fr0, *(const bf16x8*)(brow + bslot[0]*8), acc, 0,0,0);
                acc = __builtin_amdgcn_mfma_f32_32x32x16_bf16(fr1, *(const bf16x8*)(brow + bslot[1]*8), acc, 0,0,0);
                acc = __builtin_amdgcn_mfma_f32_32x32x16_bf16(fr3, *(const bf16x8*)(brow + bslot[2]*8), acc, 0,0,0);
                acc = __builtin_amdgcn_mfma_f32_32x32x16_bf16(fr4, *(const bf16x8*)(brow + bslot[3]*8), acc, 0,0,0);
                bf16x8 frWd = {};
                if (half == 0) frWd[0] = sWd[cb * 32 + l];
                acc = __builtin_amdgcn_mfma_f32_32x32x16_bf16(fr2, frWd, acc, 0,0,0);
            }
            #pragma unroll
            for (int r = 0; r < 16; ++r) {
                const int e = (r & 3) + 8 * (r >> 2) + 4 * half;
                sHdnB[wave][e][((g + (e >> 3)) & 3) * 8 + jlow] = bfc(silu_f(acc[r]));
            }
            #pragma unroll
            for (int q = 0; q < 2; ++q) {
                const int g2 = q * 2 + half;
                const bf16x8 afr = *(const bf16x8*)&sHdnB[wave][l][((g2 + (l >> 3)) & 3) * 8];
                accC = __builtin_amdgcn_mfma_f32_32x32x16_bf16(afr, w2fr[cb * 2 + q], accC, 0,0,0);
            }
        }
        if (l < 5) {
            #pragma unroll
            for (int r = 0; r < 16; ++r) {
                const int e = (r & 3) + 8 * (r >> 2) + 4 * half;
                if (e < 31) {
                    const int s_ = e + (e >= n ? 1 : 0);
                    const int ge = (mol * 32 + s_) * 31 + (n - (n > s_ ? 1 : 0));
                    outB[(size_t)ge * 5 + l] = accC[r] + be2v;
                }
            }
        }
    }
}

// ---------------------------------------------------------------------------
__global__ __launch_bounds__(256) void pos_copy(const float* __restrict__ pos,
                                                float* __restrict__ out)
{
    const int i = blockIdx.x * 256 + threadIdx.x;
    out[i] = pos[i];
}

// ---------------------------------------------------------------------------
__global__ __launch_bounds__(256) void atoms_kernel(
    const short* __restrict__ tmp, const float* __restrict__ Wh2,
    const float* __restrict__ bh2, float* __restrict__ outA)
{
    const int gid = blockIdx.x * 256 + threadIdx.x;
    const int n = gid >> 4, o = gid & 15;
    float acc = bh2[o];
    #pragma unroll 8
    for (int k = 0; k < SDIM_; ++k) acc += bf2f(tmp[(size_t)n * SDIM_ + k]) * Wh2[k * NAF_ + o];
    outA[gid] = acc;
}

// ---------------------------------------------------------------------------
extern "C" void kernel_launch(void* const* d_in, const int* in_sizes, int n_in,
                              void* d_out, int out_size, void* d_ws, size_t ws_size,
                              hipStream_t stream) {
    const float* x   = (const float*)d_in[0];
    const float* z   = (const float*)d_in[1];
    const float* rot = (const float*)d_in[2];
    const float* ea  = (const float*)d_in[4];
    const float* Wam = (const float*)d_in[6];
    const float* bam = (const float*)d_in[7];
    const float* Wbm = (const float*)d_in[8];
    const float* bbm = (const float*)d_in[9];
    const float* gW1 = (const float*)d_in[10];
    const float* gb1 = (const float*)d_in[11];
    const float* gW2 = (const float*)d_in[12];
    const float* gb2 = (const float*)d_in[13];
    const float* Wh1 = (const float*)d_in[14];
    const float* bh1 = (const float*)d_in[15];
    const float* Wh2 = (const float*)d_in[16];
    const float* bh2 = (const float*)d_in[17];
    const float* We1 = (const float*)d_in[18];
    const float* be1 = (const float*)d_in[19];
    const float* We2 = (const float*)d_in[20];
    const float* be2 = (const float*)d_in[21];
    float* out = (float*)d_out;

    float* ws  = (float*)d_ws;
    float* s   = ws;                     // 8192*256 fp32
    float* pos = ws + 2097152;           // 8192*3
    short* e   = (short*)(ws + 2121728); // 8192*31*32 bf16
    short* SAh = (short*)(ws + 10248192);// 8192*256 bf16
    short* SBh = (short*)(ws + 12345344);// 8192*256 bf16
    short* Hh  = (short*)(ws + 14442496);// 8192*256 bf16
    float* pd  = ws + 16539648;          // 8192*3
    short* tmph = SAh;                   // reuse after layers
    short* Uh   = Hh;                    // reuse after layers

    node_init<<<NN, 256, 0, stream>>>(x, z, rot, Wam, bam, s, pos);
    edge_init2<<<NN, 256, 0, stream>>>(ea, Wbm, bbm, e);

    for (int l = 0; l < LAYERS_; ++l) {
        const float* W1 = gW1 + (size_t)l * 546 * 256;
        const float* b1 = gb1 + l * 256;
        const float* W2 = gW2 + (size_t)l * 256 * 353;
        const float* b2 = gb2 + l * 353;
        gemm_dual<<<dim3(8, 64), 256, 0, stream>>>(s, W1, W1 + 256 * 256, SAh, SBh);
        edge_mfma<<<2 * N_MOLS, 512, 0, stream>>>(SAh, SBh, pos, e, W1, b1, W2, b2, Hh, pd);
        // s += (H @ W2[:,0:256])/31 + b2[0:256]; fused: pos += pd/31
        gemm_mfma<0,1,1,1,0><<<dim3(4, 64), 256, 0, stream>>>(Hh, W2, s, b2, 256, 256, 353, 1.f / 31.f, pos, pd);
    }

    gemm_mfma<1,0,0,0,1><<<dim3(4, 64), 256, 0, stream>>>(s, Wh1, tmph, bh1, 256, 256, 256, 1.f, nullptr, nullptr);
    atoms_kernel<<<512, 256, 0, stream>>>(tmph, Wh2, bh2, out);

    gemm_mfma<0,0,0,0,1><<<dim3(2, 64), 256, 0, stream>>>(s, We1, Uh, nullptr, 256, 128, 128, 1.f, nullptr, nullptr);
    bond_mfma<<<2 * N_MOLS, 512, 0, stream>>>(Uh, pos, e, We1, be1, We2, be2, out + 131072);

    pos_copy<<<96, 256, 0, stream>>>(pos, out + 131072 + 1269760);
}